// Round 9
// baseline (80.634 us; speedup 1.0000x reference)
//
#include <hip/hip_runtime.h>
#include <hip/hip_bf16.h>

// b=2, L=1024, d=1024, dt_rank=64, n=16, E=96
#define LSEQ 1024
#define DMODEL 1024
#define NSTATE 16
#define DTRANK 64
#define ECOL 96
#define MTOT 2048

typedef short s16x8 __attribute__((ext_vector_type(8)));
typedef float f32x4 __attribute__((ext_vector_type(4)));

__device__ inline unsigned short f2bf(float f) {
    unsigned int u = __builtin_bit_cast(unsigned int, f);
    u += 0x7FFFu + ((u >> 16) & 1u);
    return (unsigned short)(u >> 16);
}
__device__ inline float bf2f(unsigned short h) {
    unsigned int u = ((unsigned int)h) << 16;
    return __builtin_bit_cast(float, u);
}

__device__ inline f32x4 shflup4(f32x4 v, int off) {
    f32x4 r;
    r[0] = __shfl_up(v[0], off, 64);
    r[1] = __shfl_up(v[1], off, 64);
    r[2] = __shfl_up(v[2], off, 64);
    r[3] = __shfl_up(v[3], off, 64);
    return r;
}

// ---------------- fused prep: x->xTbf, Wx->WxT h/l, Wdt->WdtT h/l, Wout->WbfT ----------------
__global__ __launch_bounds__(256) void k_prep(const float* __restrict__ x,
                                              const float* __restrict__ Wx,
                                              const float* __restrict__ Wdt,
                                              const float* __restrict__ Wout,
                                              unsigned short* __restrict__ xTbf,
                                              unsigned short* __restrict__ WxTh,
                                              unsigned short* __restrict__ WxTl,
                                              unsigned short* __restrict__ WdtTh,
                                              unsigned short* __restrict__ WdtTl,
                                              unsigned short* __restrict__ WbfT) {
    __shared__ float t[64][65];
    int id = blockIdx.x;
    int tid = threadIdx.x;
    if (id < 512) {
        int d0 = (id & 15) * 64, m0 = (id >> 4) * 64;
        int tx = tid & 63, ty = tid >> 6;
#pragma unroll
        for (int j = 0; j < 64; j += 4)
            t[ty + j][tx] = x[(size_t)(m0 + ty + j) * 1024 + d0 + tx];
        __syncthreads();
#pragma unroll
        for (int j = 0; j < 64; j += 4)
            xTbf[(size_t)(d0 + ty + j) * 2048 + m0 + tx] = f2bf(t[tx][ty + j]);
    } else if (id < 512 + 96) {
        int id2 = id - 512;
        int e0 = (id2 % 3) * 32, k0 = (id2 / 3) * 32;
        int tx = tid & 31, ty = tid >> 5;
#pragma unroll
        for (int j = 0; j < 32; j += 8)
            t[ty + j][tx] = Wx[(size_t)(k0 + ty + j) * 96 + e0 + tx];
        __syncthreads();
#pragma unroll
        for (int j = 0; j < 32; j += 8) {
            float v = t[tx][ty + j];
            unsigned short h = f2bf(v);
            WxTh[(size_t)(e0 + ty + j) * 1024 + k0 + tx] = h;
            WxTl[(size_t)(e0 + ty + j) * 1024 + k0 + tx] = f2bf(v - bf2f(h));
        }
    } else if (id < 512 + 96 + 64) {
        int id3 = id - (512 + 96);
        int d0 = (id3 & 31) * 32, r0 = (id3 >> 5) * 32;
        int tx = tid & 31, ty = tid >> 5;
#pragma unroll
        for (int j = 0; j < 32; j += 8)
            t[ty + j][tx] = Wdt[(size_t)(r0 + ty + j) * 1024 + d0 + tx];
        __syncthreads();
#pragma unroll
        for (int j = 0; j < 32; j += 8) {
            float v = t[tx][ty + j];
            unsigned short h = f2bf(v);
            WdtTh[(size_t)(d0 + ty + j) * 64 + r0 + tx] = h;
            WdtTl[(size_t)(d0 + ty + j) * 64 + r0 + tx] = f2bf(v - bf2f(h));
        }
    } else {
        int id4 = id - (512 + 96 + 64);
        int e0 = (id4 & 15) * 64, k0 = (id4 >> 4) * 64;
        int tx = tid & 63, ty = tid >> 6;
#pragma unroll
        for (int j = 0; j < 64; j += 4)
            t[ty + j][tx] = Wout[(size_t)(k0 + ty + j) * 1024 + e0 + tx];
        __syncthreads();
#pragma unroll
        for (int j = 0; j < 64; j += 4)
            WbfT[(size_t)(e0 + ty + j) * 1024 + k0 + tx] = f2bf(t[tx][ty + j]);
    }
}

// ---------------- xdbl via MFMA split, split-K: part[slice][2048][96] (x read fp32, split in-reg) ----------------
__global__ __launch_bounds__(256) void k_xdbl3(const float* __restrict__ x,
                                               const unsigned short* __restrict__ WxTh,
                                               const unsigned short* __restrict__ WxTl,
                                               float* __restrict__ part) {
    __shared__ unsigned short Ah[32 * 64], Al[32 * 64];
    __shared__ unsigned short Bh[96 * 64], Bl[96 * 64];
    int bm = (blockIdx.x >> 2) * 32;
    int slice = blockIdx.x & 3;
    int tid = threadIdx.x, lane = tid & 63, w = tid >> 6;
    int wm = w >> 1, wn = w & 1;
    int r = lane & 15, kb = lane >> 4;

    f32x4 acc[3];
#pragma unroll
    for (int nf = 0; nf < 3; ++nf) acc[nf] = (f32x4){0.f, 0.f, 0.f, 0.f};

#pragma unroll 1
    for (int kc = 0; kc < 4; ++kc) {
        int kbase = slice * 256 + kc * 64;
        __syncthreads();
        {   // stage A: read x fp32, split to bf16 h/l in regs, swizzled LDS write
            int row = tid >> 3, cc = tid & 7;
            size_t src = (size_t)(bm + row) * 1024 + kbase + cc * 8;
            float4 v0 = *(const float4*)&x[src];
            float4 v1 = *(const float4*)&x[src + 4];
            float vv[8] = {v0.x, v0.y, v0.z, v0.w, v1.x, v1.y, v1.z, v1.w};
            s16x8 h, lo;
#pragma unroll
            for (int j = 0; j < 8; ++j) {
                unsigned short hb = f2bf(vv[j]);
                h[j] = (short)hb;
                lo[j] = (short)f2bf(vv[j] - bf2f(hb));
            }
            int dstB = row * 128 + ((cc * 16) ^ ((row & 7) << 4));
            *(s16x8*)((char*)Ah + dstB) = h;
            *(s16x8*)((char*)Al + dstB) = lo;
        }
#pragma unroll
        for (int j = 0; j < 3; ++j) {
            int c = tid + j * 256;
            int row = c >> 3, cc = c & 7;
            size_t src = (size_t)row * 1024 + kbase + cc * 8;
            int dstB = row * 128 + ((cc * 16) ^ ((row & 7) << 4));
            *(s16x8*)((char*)Bh + dstB) = *(const s16x8*)&WxTh[src];
            *(s16x8*)((char*)Bl + dstB) = *(const s16x8*)&WxTl[src];
        }
        __syncthreads();
#pragma unroll
        for (int ks = 0; ks < 2; ++ks) {
            int sw = (ks * 64 + kb * 16) ^ ((r & 7) << 4);
            s16x8 a_h = *(const s16x8*)((char*)Ah + (wm * 16 + r) * 128 + sw);
            s16x8 a_l = *(const s16x8*)((char*)Al + (wm * 16 + r) * 128 + sw);
#pragma unroll
            for (int nf = 0; nf < 3; ++nf) {
                int brow = wn * 48 + nf * 16 + r;
                s16x8 b_h = *(const s16x8*)((char*)Bh + brow * 128 + sw);
                s16x8 b_l = *(const s16x8*)((char*)Bl + brow * 128 + sw);
                acc[nf] = __builtin_amdgcn_mfma_f32_16x16x32_bf16(a_h, b_h, acc[nf], 0, 0, 0);
                acc[nf] = __builtin_amdgcn_mfma_f32_16x16x32_bf16(a_h, b_l, acc[nf], 0, 0, 0);
                acc[nf] = __builtin_amdgcn_mfma_f32_16x16x32_bf16(a_l, b_h, acc[nf], 0, 0, 0);
            }
        }
    }
    float* pb = part + (size_t)slice * 2048 * 96;
#pragma unroll
    for (int nf = 0; nf < 3; ++nf)
#pragma unroll
        for (int j = 0; j < 4; ++j)
            pb[(size_t)(bm + wm * 16 + kb * 4 + j) * 96 + wn * 48 + nf * 16 + r] = acc[nf][j];
}

// ---------------- delta via MFMA (fused part-reduce): M-tile 128, N-tile 64, K=64 ----------------
__global__ __launch_bounds__(256) void k_delta2(const float* __restrict__ part,
                                                const unsigned short* __restrict__ WdtTh,
                                                const unsigned short* __restrict__ WdtTl,
                                                const float* __restrict__ bdt,
                                                float* __restrict__ deltaT,
                                                float* __restrict__ bpk,
                                                float* __restrict__ cpk) {
    __shared__ char pool[34816];
    unsigned short* Ah = (unsigned short*)pool;
    unsigned short* Al = (unsigned short*)(pool + 16384);
    float (*slab)[32][68] = (float (*)[32][68])pool;

    int bm = blockIdx.y * 128;
    int bn = blockIdx.x * 64;
    int tid = threadIdx.x, lane = tid & 63, w = tid >> 6;
    int wm = w >> 1, wn = w & 1;
    int r = lane & 15, kb = lane >> 4;

#pragma unroll
    for (int i = 0; i < 8; ++i) {
        int q = tid + i * 256;
        int row = q >> 4, c4 = q & 15;
        size_t off = (size_t)(bm + row) * 96 + c4 * 4;
        f32x4 v = *(const f32x4*)&part[off];
#pragma unroll
        for (int s = 1; s < 4; ++s) v += *(const f32x4*)&part[(size_t)s * 2048 * 96 + off];
        ushort4 h4, l4;
        h4.x = f2bf(v[0]); l4.x = f2bf(v[0] - bf2f(h4.x));
        h4.y = f2bf(v[1]); l4.y = f2bf(v[1] - bf2f(h4.y));
        h4.z = f2bf(v[2]); l4.z = f2bf(v[2] - bf2f(h4.z));
        h4.w = f2bf(v[3]); l4.w = f2bf(v[3] - bf2f(h4.w));
        int dstB = row * 128 + ((c4 * 8) ^ ((row & 7) << 4));
        *(ushort4*)((char*)Ah + dstB) = h4;
        *(ushort4*)((char*)Al + dstB) = l4;
    }
    if (blockIdx.x == 0) {
#pragma unroll
        for (int i = 0; i < 4; ++i) {
            int q = tid + i * 256;
            int row = q >> 3, c4 = q & 7;
            size_t off = (size_t)(bm + row) * 96 + 64 + c4 * 4;
            f32x4 v = *(const f32x4*)&part[off];
#pragma unroll
            for (int s = 1; s < 4; ++s) v += *(const f32x4*)&part[(size_t)s * 2048 * 96 + off];
            if (c4 < 4) *(f32x4*)&bpk[(size_t)(bm + row) * 16 + c4 * 4] = v;
            else        *(f32x4*)&cpk[(size_t)(bm + row) * 16 + (c4 - 4) * 4] = v;
        }
    }
    __syncthreads();

    f32x4 acc[4][2];
#pragma unroll
    for (int mf = 0; mf < 4; ++mf)
#pragma unroll
        for (int nf = 0; nf < 2; ++nf) acc[mf][nf] = (f32x4){0.f, 0.f, 0.f, 0.f};

#pragma unroll
    for (int ks = 0; ks < 2; ++ks) {
        int sw = (ks * 64 + kb * 16) ^ ((r & 7) << 4);
        s16x8 Afh[4], Afl[4], Bh[2], Bl[2];
#pragma unroll
        for (int mf = 0; mf < 4; ++mf) {
            int arow = wm * 64 + mf * 16 + r;
            Afh[mf] = *(const s16x8*)((char*)Ah + arow * 128 + sw);
            Afl[mf] = *(const s16x8*)((char*)Al + arow * 128 + sw);
        }
#pragma unroll
        for (int nf = 0; nf < 2; ++nf) {
            size_t b = (size_t)(bn + wn * 32 + nf * 16 + r) * 64 + ks * 32 + kb * 8;
            Bh[nf] = *(const s16x8*)&WdtTh[b];
            Bl[nf] = *(const s16x8*)&WdtTl[b];
        }
#pragma unroll
        for (int mf = 0; mf < 4; ++mf)
#pragma unroll
            for (int nf = 0; nf < 2; ++nf) {
                acc[mf][nf] = __builtin_amdgcn_mfma_f32_16x16x32_bf16(Afh[mf], Bh[nf], acc[mf][nf], 0, 0, 0);
                acc[mf][nf] = __builtin_amdgcn_mfma_f32_16x16x32_bf16(Afh[mf], Bl[nf], acc[mf][nf], 0, 0, 0);
                acc[mf][nf] = __builtin_amdgcn_mfma_f32_16x16x32_bf16(Afl[mf], Bh[nf], acc[mf][nf], 0, 0, 0);
            }
    }
    __syncthreads();

#pragma unroll
    for (int nf = 0; nf < 2; ++nf) {
        float bb = bdt[bn + wn * 32 + nf * 16 + r];
#pragma unroll
        for (int mf = 0; mf < 4; ++mf)
#pragma unroll
            for (int j = 0; j < 4; ++j) {
                float z = acc[mf][nf][j] + bb;
                float sp = fmaxf(z, 0.f) + log1pf(expf(-fabsf(z)));
                slab[w][nf * 16 + r][mf * 16 + kb * 4 + j] = sp;
            }
    }
#pragma unroll
    for (int i = 0; i < 8; ++i) {
        int idx = i * 64 + lane;
        int dl = idx >> 4, mq = (idx & 15) * 4;
        f32x4 v = *(const f32x4*)&slab[w][dl][mq];
        *(f32x4*)&deltaT[(size_t)(bn + wn * 32 + dl) * MTOT + bm + wm * 64 + mq] = v;
    }
}

// ---------------- Kernel C: d-batched (DG=4) chunked selective scan -> yT bf16 [d][m] ----------------
__global__ __launch_bounds__(256) void k_scan4(const float* __restrict__ deltaT,
                                               const unsigned short* __restrict__ xTbf,
                                               const float* __restrict__ bpk,
                                               const float* __restrict__ cpk,
                                               const float* __restrict__ Alog,
                                               const float* __restrict__ Dp,
                                               unsigned short* __restrict__ yTbf) {
    __shared__ double csum[64][4];
    __shared__ double Rbef[64][4];
    __shared__ float TcL[64][4][4][4];   // [c][dg][l][j]
    __shared__ float syp[4][64 * 17];

    int tid = threadIdx.x;
    int c = tid >> 2, l = tid & 3;
    int w = tid >> 6, lane = tid & 63;
    int dgrp = blockIdx.x & 255, b = blockIdx.x >> 8;
    int d0 = dgrp * 4;
    int m0 = b * 1024;

    const f32x4* dp[4];
    const unsigned short* up[4];
#pragma unroll
    for (int dg = 0; dg < 4; ++dg) {
        dp[dg] = (const f32x4*)(deltaT + (size_t)(d0 + dg) * MTOT + m0 + c * 16);
        up[dg] = xTbf + (size_t)(d0 + dg) * MTOT + m0 + c * 16;
    }

    // chunk delta sums (double) per d
#pragma unroll
    for (int dg = 0; dg < 4; ++dg) {
        double s = 0.0;
#pragma unroll
        for (int i = 0; i < 4; ++i) {
            f32x4 v = dp[dg][i];
            s += (double)v[0] + (double)v[1] + (double)v[2] + (double)v[3];
        }
        if (l == 0) csum[c][dg] = s;
    }
    __syncthreads();
    // wave w: inclusive suffix sum over 64 chunks for dg=w
    {
        double v = csum[lane][w];
#pragma unroll
        for (int off = 1; off < 64; off <<= 1) {
            double t = __shfl_down(v, off, 64);
            if (lane + off < 64) v += t;
        }
        Rbef[lane][w] = v;
    }
    __syncthreads();

    float Af[4][4], Sb[4][4];
#pragma unroll
    for (int dg = 0; dg < 4; ++dg) {
        double Rb = Rbef[c][dg];
#pragma unroll
        for (int j = 0; j < 4; ++j) {
            Af[dg][j] = -__expf(Alog[(d0 + dg) * NSTATE + 4 * l + j]);
            Sb[dg][j] = (float)((double)Af[dg][j] * Rb);
        }
    }

    const f32x4* Bp = (const f32x4*)bpk + (size_t)(m0 + c * 16) * 4 + l;
    const f32x4* Cp = (const f32x4*)cpk + (size_t)(m0 + c * 16) * 4 + l;

    // ---- pass 1 ----
    float P[4] = {0.f, 0.f, 0.f, 0.f};
    f32x4 Tn[4];
#pragma unroll
    for (int dg = 0; dg < 4; ++dg) Tn[dg] = (f32x4){0.f, 0.f, 0.f, 0.f};
#pragma unroll 1
    for (int t4 = 0; t4 < 4; ++t4) {
        f32x4 Bq[4];
#pragma unroll
        for (int k = 0; k < 4; ++k) Bq[k] = Bp[(t4 * 4 + k) * 4];
        f32x4 rdv[4];
        float ru[4][4];
#pragma unroll
        for (int dg = 0; dg < 4; ++dg) {
            rdv[dg] = dp[dg][t4];
            ushort4 uv = *(const ushort4*)(up[dg] + t4 * 4);
            ru[dg][0] = bf2f(uv.x); ru[dg][1] = bf2f(uv.y);
            ru[dg][2] = bf2f(uv.z); ru[dg][3] = bf2f(uv.w);
        }
#pragma unroll
        for (int k = 0; k < 4; ++k)
#pragma unroll
            for (int dg = 0; dg < 4; ++dg) {
                float dlt = rdv[dg][k];
                P[dg] += dlt;
                float du = dlt * ru[dg][k];
#pragma unroll
                for (int j = 0; j < 4; ++j) {
                    float e = __expf(fmaf(-Af[dg][j], P[dg], Sb[dg][j]));
                    Tn[dg][j] = fmaf(du * Bq[k][j], e, Tn[dg][j]);
                }
            }
    }
#pragma unroll
    for (int dg = 0; dg < 4; ++dg) *(f32x4*)&TcL[c][dg][l][0] = Tn[dg];
    __syncthreads();

    // exclusive prefix over chunks; wave w handles dg=w, loop over l2
#pragma unroll
    for (int l2 = 0; l2 < 4; ++l2) {
        f32x4 v = *(const f32x4*)&TcL[lane][w][l2][0];
#pragma unroll
        for (int off = 1; off < 64; off <<= 1) {
            f32x4 t = shflup4(v, off);
            if (lane >= off) v += t;
        }
        f32x4 ex = shflup4(v, 1);
        if (lane == 0) ex = (f32x4){0.f, 0.f, 0.f, 0.f};
        *(f32x4*)&TcL[lane][w][l2][0] = ex;
    }
    __syncthreads();

    f32x4 num[4];
#pragma unroll
    for (int dg = 0; dg < 4; ++dg) num[dg] = *(const f32x4*)&TcL[c][dg][l][0];

    float Dv[4];
#pragma unroll
    for (int dg = 0; dg < 4; ++dg) { Dv[dg] = Dp[d0 + dg]; P[dg] = 0.f; }

    // ---- pass 2 ----
#pragma unroll 1
    for (int t4 = 0; t4 < 4; ++t4) {
        f32x4 Bq[4], Cq[4];
#pragma unroll
        for (int k = 0; k < 4; ++k) {
            Bq[k] = Bp[(t4 * 4 + k) * 4];
            Cq[k] = Cp[(t4 * 4 + k) * 4];
        }
        f32x4 rdv[4];
        float ru[4][4];
#pragma unroll
        for (int dg = 0; dg < 4; ++dg) {
            rdv[dg] = dp[dg][t4];
            ushort4 uv = *(const ushort4*)(up[dg] + t4 * 4);
            ru[dg][0] = bf2f(uv.x); ru[dg][1] = bf2f(uv.y);
            ru[dg][2] = bf2f(uv.z); ru[dg][3] = bf2f(uv.w);
        }
#pragma unroll
        for (int k = 0; k < 4; ++k) {
            float psum[4];
#pragma unroll
            for (int dg = 0; dg < 4; ++dg) {
                float dlt = rdv[dg][k];
                P[dg] += dlt;
                float du = dlt * ru[dg][k];
                float ps = 0.f;
#pragma unroll
                for (int j = 0; j < 4; ++j) {
                    float e = __expf(fmaf(-Af[dg][j], P[dg], Sb[dg][j]));
                    num[dg][j] = fmaf(du * Bq[k][j], e, num[dg][j]);
                    float rr = __builtin_amdgcn_rcpf(e + 1e-12f);
                    ps = fmaf(num[dg][j] * rr, Cq[k][j], ps);
                }
                psum[dg] = ps;
            }
#pragma unroll
            for (int dg = 0; dg < 4; ++dg) {
                float ps = psum[dg];
                ps += __shfl_xor(ps, 1);
                ps += __shfl_xor(ps, 2);
                if (l == 0) syp[dg][c * 17 + t4 * 4 + k] = fmaf(ru[dg][k], Dv[dg], ps);
            }
        }
    }
    __syncthreads();
    {
        int cc = tid >> 2, oo = (tid & 3) * 4;
#pragma unroll
        for (int dg = 0; dg < 4; ++dg) {
            const float* sp = &syp[dg][cc * 17 + oo];
            ushort4 o;
            o.x = f2bf(sp[0]);
            o.y = f2bf(sp[1]);
            o.z = f2bf(sp[2]);
            o.w = f2bf(sp[3]);
            *reinterpret_cast<ushort4*>(&yTbf[(size_t)(d0 + dg) * MTOT + m0 + tid * 4]) = o;
        }
    }
}

// ---------------- yTbf [d][m] bf16 -> ybf [m][d] bf16 ----------------
__global__ __launch_bounds__(256) void k_ytr(const unsigned short* __restrict__ in,
                                             unsigned short* __restrict__ out) {
    __shared__ unsigned short t[64][66];
    int d0 = blockIdx.y * 64, m0 = blockIdx.x * 64;
    int tx = threadIdx.x & 63, ty = threadIdx.x >> 6;
#pragma unroll
    for (int j = 0; j < 64; j += 4)
        t[ty + j][tx] = in[(size_t)(d0 + ty + j) * MTOT + m0 + tx];
    __syncthreads();
#pragma unroll
    for (int j = 0; j < 64; j += 4)
        out[(size_t)(m0 + ty + j) * 1024 + d0 + tx] = t[tx][ty + j];
}

// ---------------- Kernel D: out = ybf @ WbfT^T + b_out via MFMA, BM=64, grid 512 ----------------
__global__ __launch_bounds__(256) void k_gemm(const unsigned short* __restrict__ A,
                                              const unsigned short* __restrict__ B,
                                              const float* __restrict__ bias,
                                              float* __restrict__ out) {
    __shared__ unsigned short As[64 * 64];
    __shared__ unsigned short Bs[64 * 64];
    const int GN = 1024, GK = 1024;
    int bm = blockIdx.y * 64;
    int bn = blockIdx.x * 64;
    int tid = threadIdx.x;
    int lane = tid & 63;
    int w = tid >> 6;
    int wm = w >> 1, wn = w & 1;
    int r = lane & 15, kb = lane >> 4;

    f32x4 acc[2][2];
#pragma unroll
    for (int mf = 0; mf < 2; ++mf)
#pragma unroll
        for (int nf = 0; nf < 2; ++nf) acc[mf][nf] = (f32x4){0.f, 0.f, 0.f, 0.f};

    s16x8 ra[2], rb[2];
    auto stage_load = [&](int k0) {
#pragma unroll
        for (int i = 0; i < 2; ++i) {
            int q = tid + i * 256;
            ra[i] = *reinterpret_cast<const s16x8*>(&A[(size_t)(bm + (q >> 3)) * GK + k0 + (q & 7) * 8]);
            rb[i] = *reinterpret_cast<const s16x8*>(&B[(size_t)(bn + (q >> 3)) * GK + k0 + (q & 7) * 8]);
        }
    };

    stage_load(0);
    for (int k0 = 0; k0 < GK; k0 += 64) {
        __syncthreads();
#pragma unroll
        for (int i = 0; i < 2; ++i) {
            int q = tid + i * 256;
            int row = q >> 3;
            int dstB = row * 128 + (((q & 7) * 16) ^ ((row & 7) << 4));
            *(s16x8*)((char*)As + dstB) = ra[i];
            *(s16x8*)((char*)Bs + dstB) = rb[i];
        }
        __syncthreads();
        if (k0 + 64 < GK) stage_load(k0 + 64);
#pragma unroll
        for (int ks = 0; ks < 2; ++ks) {
            int sw = (ks * 64 + kb * 16) ^ ((r & 7) << 4);
            s16x8 af[2], bfr[2];
#pragma unroll
            for (int mf = 0; mf < 2; ++mf)
                af[mf] = *(const s16x8*)((char*)As + (wm * 32 + mf * 16 + r) * 128 + sw);
#pragma unroll
            for (int nf = 0; nf < 2; ++nf)
                bfr[nf] = *(const s16x8*)((char*)Bs + (wn * 32 + nf * 16 + r) * 128 + sw);
#pragma unroll
            for (int mf = 0; mf < 2; ++mf)
#pragma unroll
                for (int nf = 0; nf < 2; ++nf)
                    acc[mf][nf] = __builtin_amdgcn_mfma_f32_16x16x32_bf16(af[mf], bfr[nf], acc[mf][nf], 0, 0, 0);
        }
    }
#pragma unroll
    for (int nf = 0; nf < 2; ++nf) {
        float bb = bias[bn + wn * 32 + nf * 16 + r];
#pragma unroll
        for (int mf = 0; mf < 2; ++mf)
#pragma unroll
            for (int j = 0; j < 4; ++j)
                out[(size_t)(bm + wm * 32 + mf * 16 + kb * 4 + j) * GN + bn + wn * 32 + nf * 16 + r] =
                    acc[mf][nf][j] + bb;
    }
}

extern "C" void kernel_launch(void* const* d_in, const int* in_sizes, int n_in,
                              void* d_out, int out_size, void* d_ws, size_t ws_size,
                              hipStream_t stream) {
    const float* x    = (const float*)d_in[0];
    const float* Wx   = (const float*)d_in[1];
    const float* Wdt  = (const float*)d_in[2];
    const float* bdt  = (const float*)d_in[3];
    const float* Alog = (const float*)d_in[4];
    const float* Dp   = (const float*)d_in[5];
    const float* Wout = (const float*)d_in[6];
    const float* bout = (const float*)d_in[7];
    float* out = (float*)d_out;

    float* deltaT = (float*)d_ws;                          // 1024*2048 f
    float* bpk    = deltaT + 1024 * 2048;                  // 2048*16 f
    float* cpk    = bpk + 2048 * 16;                       // 2048*16 f
    float* part   = cpk + 2048 * 16;                       // 4*2048*96 f
    unsigned short* xTbf  = (unsigned short*)(part + 4 * 2048 * 96);  // 1024*2048
    unsigned short* WxTh  = xTbf + 1024 * 2048;            // 96*1024
    unsigned short* WxTl  = WxTh + 96 * 1024;
    unsigned short* WdtTh = WxTl + 96 * 1024;              // 1024*64
    unsigned short* WdtTl = WdtTh + 1024 * 64;
    unsigned short* yTbf  = WdtTl + 1024 * 64;             // 1024*2048
    unsigned short* ybf   = yTbf + 1024 * 2048;            // 2048*1024
    unsigned short* WbfT  = ybf + 2048 * 1024;             // 1024*1024

    k_prep<<<928, 256, 0, stream>>>(x, Wx, Wdt, Wout, xTbf,
                                    WxTh, WxTl, WdtTh, WdtTl, WbfT);
    k_xdbl3<<<256, 256, 0, stream>>>(x, WxTh, WxTl, part);
    k_delta2<<<dim3(16, 16), 256, 0, stream>>>(part, WdtTh, WdtTl, bdt, deltaT, bpk, cpk);
    k_scan4<<<512, 256, 0, stream>>>(deltaT, xTbf, bpk, cpk, Alog, Dp, yTbf);
    k_ytr<<<dim3(32, 16), 256, 0, stream>>>(yTbf, ybf);
    k_gemm<<<dim3(16, 32), 256, 0, stream>>>(ybf, WbfT, bout, out);
}

// Round 10
// 75.741 us; speedup vs baseline: 1.0646x; 1.0646x over previous
//
#include <hip/hip_runtime.h>
#include <hip/hip_bf16.h>

// b=2, L=1024, d=1024, dt_rank=64, n=16, E=96
#define LSEQ 1024
#define DMODEL 1024
#define NSTATE 16
#define DTRANK 64
#define ECOL 96
#define MTOT 2048

typedef short s16x8 __attribute__((ext_vector_type(8)));
typedef float f32x4 __attribute__((ext_vector_type(4)));

#if __has_builtin(__builtin_amdgcn_exp2f)
#define EXP2F(x) __builtin_amdgcn_exp2f(x)
#else
#define EXP2F(x) exp2f(x)
#endif
#define LOG2E 1.4426950408889634

__device__ inline unsigned short f2bf(float f) {
    unsigned int u = __builtin_bit_cast(unsigned int, f);
    u += 0x7FFFu + ((u >> 16) & 1u);
    return (unsigned short)(u >> 16);
}
__device__ inline float bf2f(unsigned short h) {
    unsigned int u = ((unsigned int)h) << 16;
    return __builtin_bit_cast(float, u);
}

__device__ inline f32x4 shflup4(f32x4 v, int off) {
    f32x4 r;
    r[0] = __shfl_up(v[0], off, 64);
    r[1] = __shfl_up(v[1], off, 64);
    r[2] = __shfl_up(v[2], off, 64);
    r[3] = __shfl_up(v[3], off, 64);
    return r;
}

// ---------------- fused prep: x->xTbf, Wx->WxT h/l, Wdt->WdtT h/l, Wout->WbfT ----------------
__global__ __launch_bounds__(256) void k_prep(const float* __restrict__ x,
                                              const float* __restrict__ Wx,
                                              const float* __restrict__ Wdt,
                                              const float* __restrict__ Wout,
                                              unsigned short* __restrict__ xTbf,
                                              unsigned short* __restrict__ WxTh,
                                              unsigned short* __restrict__ WxTl,
                                              unsigned short* __restrict__ WdtTh,
                                              unsigned short* __restrict__ WdtTl,
                                              unsigned short* __restrict__ WbfT) {
    __shared__ float t[64][65];
    int id = blockIdx.x;
    int tid = threadIdx.x;
    if (id < 512) {
        int d0 = (id & 15) * 64, m0 = (id >> 4) * 64;
        int tx = tid & 63, ty = tid >> 6;
#pragma unroll
        for (int j = 0; j < 64; j += 4)
            t[ty + j][tx] = x[(size_t)(m0 + ty + j) * 1024 + d0 + tx];
        __syncthreads();
#pragma unroll
        for (int j = 0; j < 64; j += 4)
            xTbf[(size_t)(d0 + ty + j) * 2048 + m0 + tx] = f2bf(t[tx][ty + j]);
    } else if (id < 512 + 96) {
        int id2 = id - 512;
        int e0 = (id2 % 3) * 32, k0 = (id2 / 3) * 32;
        int tx = tid & 31, ty = tid >> 5;
#pragma unroll
        for (int j = 0; j < 32; j += 8)
            t[ty + j][tx] = Wx[(size_t)(k0 + ty + j) * 96 + e0 + tx];
        __syncthreads();
#pragma unroll
        for (int j = 0; j < 32; j += 8) {
            float v = t[tx][ty + j];
            unsigned short h = f2bf(v);
            WxTh[(size_t)(e0 + ty + j) * 1024 + k0 + tx] = h;
            WxTl[(size_t)(e0 + ty + j) * 1024 + k0 + tx] = f2bf(v - bf2f(h));
        }
    } else if (id < 512 + 96 + 64) {
        int id3 = id - (512 + 96);
        int d0 = (id3 & 31) * 32, r0 = (id3 >> 5) * 32;
        int tx = tid & 31, ty = tid >> 5;
#pragma unroll
        for (int j = 0; j < 32; j += 8)
            t[ty + j][tx] = Wdt[(size_t)(r0 + ty + j) * 1024 + d0 + tx];
        __syncthreads();
#pragma unroll
        for (int j = 0; j < 32; j += 8) {
            float v = t[tx][ty + j];
            unsigned short h = f2bf(v);
            WdtTh[(size_t)(d0 + ty + j) * 64 + r0 + tx] = h;
            WdtTl[(size_t)(d0 + ty + j) * 64 + r0 + tx] = f2bf(v - bf2f(h));
        }
    } else {
        int id4 = id - (512 + 96 + 64);
        int e0 = (id4 & 15) * 64, k0 = (id4 >> 4) * 64;
        int tx = tid & 63, ty = tid >> 6;
#pragma unroll
        for (int j = 0; j < 64; j += 4)
            t[ty + j][tx] = Wout[(size_t)(k0 + ty + j) * 1024 + e0 + tx];
        __syncthreads();
#pragma unroll
        for (int j = 0; j < 64; j += 4)
            WbfT[(size_t)(e0 + ty + j) * 1024 + k0 + tx] = f2bf(t[tx][ty + j]);
    }
}

// ---------------- xdbl via MFMA split, split-K: part[slice][2048][96] ----------------
__global__ __launch_bounds__(256) void k_xdbl3(const float* __restrict__ x,
                                               const unsigned short* __restrict__ WxTh,
                                               const unsigned short* __restrict__ WxTl,
                                               float* __restrict__ part) {
    __shared__ unsigned short Ah[32 * 64], Al[32 * 64];
    __shared__ unsigned short Bh[96 * 64], Bl[96 * 64];
    int bm = (blockIdx.x >> 2) * 32;
    int slice = blockIdx.x & 3;
    int tid = threadIdx.x, lane = tid & 63, w = tid >> 6;
    int wm = w >> 1, wn = w & 1;
    int r = lane & 15, kb = lane >> 4;

    f32x4 acc[3];
#pragma unroll
    for (int nf = 0; nf < 3; ++nf) acc[nf] = (f32x4){0.f, 0.f, 0.f, 0.f};

#pragma unroll 1
    for (int kc = 0; kc < 4; ++kc) {
        int kbase = slice * 256 + kc * 64;
        __syncthreads();
        {
            int row = tid >> 3, cc = tid & 7;
            size_t src = (size_t)(bm + row) * 1024 + kbase + cc * 8;
            float4 v0 = *(const float4*)&x[src];
            float4 v1 = *(const float4*)&x[src + 4];
            float vv[8] = {v0.x, v0.y, v0.z, v0.w, v1.x, v1.y, v1.z, v1.w};
            s16x8 h, lo;
#pragma unroll
            for (int j = 0; j < 8; ++j) {
                unsigned short hb = f2bf(vv[j]);
                h[j] = (short)hb;
                lo[j] = (short)f2bf(vv[j] - bf2f(hb));
            }
            int dstB = row * 128 + ((cc * 16) ^ ((row & 7) << 4));
            *(s16x8*)((char*)Ah + dstB) = h;
            *(s16x8*)((char*)Al + dstB) = lo;
        }
#pragma unroll
        for (int j = 0; j < 3; ++j) {
            int c = tid + j * 256;
            int row = c >> 3, cc = c & 7;
            size_t src = (size_t)row * 1024 + kbase + cc * 8;
            int dstB = row * 128 + ((cc * 16) ^ ((row & 7) << 4));
            *(s16x8*)((char*)Bh + dstB) = *(const s16x8*)&WxTh[src];
            *(s16x8*)((char*)Bl + dstB) = *(const s16x8*)&WxTl[src];
        }
        __syncthreads();
#pragma unroll
        for (int ks = 0; ks < 2; ++ks) {
            int sw = (ks * 64 + kb * 16) ^ ((r & 7) << 4);
            s16x8 a_h = *(const s16x8*)((char*)Ah + (wm * 16 + r) * 128 + sw);
            s16x8 a_l = *(const s16x8*)((char*)Al + (wm * 16 + r) * 128 + sw);
#pragma unroll
            for (int nf = 0; nf < 3; ++nf) {
                int brow = wn * 48 + nf * 16 + r;
                s16x8 b_h = *(const s16x8*)((char*)Bh + brow * 128 + sw);
                s16x8 b_l = *(const s16x8*)((char*)Bl + brow * 128 + sw);
                acc[nf] = __builtin_amdgcn_mfma_f32_16x16x32_bf16(a_h, b_h, acc[nf], 0, 0, 0);
                acc[nf] = __builtin_amdgcn_mfma_f32_16x16x32_bf16(a_h, b_l, acc[nf], 0, 0, 0);
                acc[nf] = __builtin_amdgcn_mfma_f32_16x16x32_bf16(a_l, b_h, acc[nf], 0, 0, 0);
            }
        }
    }
    float* pb = part + (size_t)slice * 2048 * 96;
#pragma unroll
    for (int nf = 0; nf < 3; ++nf)
#pragma unroll
        for (int j = 0; j < 4; ++j)
            pb[(size_t)(bm + wm * 16 + kb * 4 + j) * 96 + wn * 48 + nf * 16 + r] = acc[nf][j];
}

// ---------------- delta via MFMA (fused part-reduce): M-tile 128, N-tile 64, K=64 ----------------
__global__ __launch_bounds__(256) void k_delta2(const float* __restrict__ part,
                                                const unsigned short* __restrict__ WdtTh,
                                                const unsigned short* __restrict__ WdtTl,
                                                const float* __restrict__ bdt,
                                                float* __restrict__ deltaT,
                                                float* __restrict__ bpk,
                                                float* __restrict__ cpk) {
    __shared__ char pool[34816];
    unsigned short* Ah = (unsigned short*)pool;
    unsigned short* Al = (unsigned short*)(pool + 16384);
    float (*slab)[32][68] = (float (*)[32][68])pool;

    int bm = blockIdx.y * 128;
    int bn = blockIdx.x * 64;
    int tid = threadIdx.x, lane = tid & 63, w = tid >> 6;
    int wm = w >> 1, wn = w & 1;
    int r = lane & 15, kb = lane >> 4;

#pragma unroll
    for (int i = 0; i < 8; ++i) {
        int q = tid + i * 256;
        int row = q >> 4, c4 = q & 15;
        size_t off = (size_t)(bm + row) * 96 + c4 * 4;
        f32x4 v = *(const f32x4*)&part[off];
#pragma unroll
        for (int s = 1; s < 4; ++s) v += *(const f32x4*)&part[(size_t)s * 2048 * 96 + off];
        ushort4 h4, l4;
        h4.x = f2bf(v[0]); l4.x = f2bf(v[0] - bf2f(h4.x));
        h4.y = f2bf(v[1]); l4.y = f2bf(v[1] - bf2f(h4.y));
        h4.z = f2bf(v[2]); l4.z = f2bf(v[2] - bf2f(h4.z));
        h4.w = f2bf(v[3]); l4.w = f2bf(v[3] - bf2f(h4.w));
        int dstB = row * 128 + ((c4 * 8) ^ ((row & 7) << 4));
        *(ushort4*)((char*)Ah + dstB) = h4;
        *(ushort4*)((char*)Al + dstB) = l4;
    }
    if (blockIdx.x == 0) {
#pragma unroll
        for (int i = 0; i < 4; ++i) {
            int q = tid + i * 256;
            int row = q >> 3, c4 = q & 7;
            size_t off = (size_t)(bm + row) * 96 + 64 + c4 * 4;
            f32x4 v = *(const f32x4*)&part[off];
#pragma unroll
            for (int s = 1; s < 4; ++s) v += *(const f32x4*)&part[(size_t)s * 2048 * 96 + off];
            if (c4 < 4) *(f32x4*)&bpk[(size_t)(bm + row) * 16 + c4 * 4] = v;
            else        *(f32x4*)&cpk[(size_t)(bm + row) * 16 + (c4 - 4) * 4] = v;
        }
    }
    __syncthreads();

    f32x4 acc[4][2];
#pragma unroll
    for (int mf = 0; mf < 4; ++mf)
#pragma unroll
        for (int nf = 0; nf < 2; ++nf) acc[mf][nf] = (f32x4){0.f, 0.f, 0.f, 0.f};

#pragma unroll
    for (int ks = 0; ks < 2; ++ks) {
        int sw = (ks * 64 + kb * 16) ^ ((r & 7) << 4);
        s16x8 Afh[4], Afl[4], Bh[2], Bl[2];
#pragma unroll
        for (int mf = 0; mf < 4; ++mf) {
            int arow = wm * 64 + mf * 16 + r;
            Afh[mf] = *(const s16x8*)((char*)Ah + arow * 128 + sw);
            Afl[mf] = *(const s16x8*)((char*)Al + arow * 128 + sw);
        }
#pragma unroll
        for (int nf = 0; nf < 2; ++nf) {
            size_t b = (size_t)(bn + wn * 32 + nf * 16 + r) * 64 + ks * 32 + kb * 8;
            Bh[nf] = *(const s16x8*)&WdtTh[b];
            Bl[nf] = *(const s16x8*)&WdtTl[b];
        }
#pragma unroll
        for (int mf = 0; mf < 4; ++mf)
#pragma unroll
            for (int nf = 0; nf < 2; ++nf) {
                acc[mf][nf] = __builtin_amdgcn_mfma_f32_16x16x32_bf16(Afh[mf], Bh[nf], acc[mf][nf], 0, 0, 0);
                acc[mf][nf] = __builtin_amdgcn_mfma_f32_16x16x32_bf16(Afh[mf], Bl[nf], acc[mf][nf], 0, 0, 0);
                acc[mf][nf] = __builtin_amdgcn_mfma_f32_16x16x32_bf16(Afl[mf], Bh[nf], acc[mf][nf], 0, 0, 0);
            }
    }
    __syncthreads();

#pragma unroll
    for (int nf = 0; nf < 2; ++nf) {
        float bb = bdt[bn + wn * 32 + nf * 16 + r];
#pragma unroll
        for (int mf = 0; mf < 4; ++mf)
#pragma unroll
            for (int j = 0; j < 4; ++j) {
                float z = acc[mf][nf][j] + bb;
                float sp = fmaxf(z, 0.f) + log1pf(expf(-fabsf(z)));
                slab[w][nf * 16 + r][mf * 16 + kb * 4 + j] = sp;
            }
    }
#pragma unroll
    for (int i = 0; i < 8; ++i) {
        int idx = i * 64 + lane;
        int dl = idx >> 4, mq = (idx & 15) * 4;
        f32x4 v = *(const f32x4*)&slab[w][dl][mq];
        *(f32x4*)&deltaT[(size_t)(bn + wn * 32 + dl) * MTOT + bm + wm * 64 + mq] = v;
    }
}

// ---------------- Kernel C: chunked selective scan (single-d, bf16 u, base-2 exp) ----------------
__global__ __launch_bounds__(256) void k_scan3(const float* __restrict__ deltaT,
                                               const unsigned short* __restrict__ xTbf,
                                               const float* __restrict__ bpk,
                                               const float* __restrict__ cpk,
                                               const float* __restrict__ Alog,
                                               const float* __restrict__ Dp,
                                               unsigned short* __restrict__ yTbf) {
    __shared__ double csum[64];
    __shared__ double Rbef[64];
    __shared__ float TcL[64 * 20];
    __shared__ float syp[64 * 17];

    int tid = threadIdx.x;
    int c = tid >> 2, l = tid & 3;
    int w = tid >> 6, lane = tid & 63;
    int d = blockIdx.x & 1023, b = blockIdx.x >> 10;
    int m0 = b * 1024;

    const f32x4* dp = (const f32x4*)(deltaT + (size_t)d * MTOT + m0 + c * 16);
    const unsigned short* up = xTbf + (size_t)d * MTOT + m0 + c * 16;
    const f32x4* Bp = (const f32x4*)bpk + (size_t)(m0 + c * 16) * 4 + l;
    const f32x4* Cp = (const f32x4*)cpk + (size_t)(m0 + c * 16) * 4 + l;

    double dsum = 0.0;
#pragma unroll
    for (int i = 0; i < 4; ++i) {
        f32x4 v = dp[i];
        dsum += (double)v[0] + (double)v[1] + (double)v[2] + (double)v[3];
    }
    if (l == 0) csum[c] = dsum;
    __syncthreads();
    if (tid < 64) {
        double v = csum[tid];
#pragma unroll
        for (int off = 1; off < 64; off <<= 1) {
            double t = __shfl_down(v, off, 64);
            if (tid + off < 64) v += t;
        }
        Rbef[tid] = v;
    }
    __syncthreads();

    // base-2 exponent: e = exp2(Sb2 - Af2*P), Af2 = A*log2e, Sb2 = A*Rb*log2e
    float Af2[4], Sb2[4];
    double Rb = Rbef[c];
#pragma unroll
    for (int j = 0; j < 4; ++j) {
        float Af = -__expf(Alog[d * NSTATE + 4 * l + j]);
        double A2 = (double)Af * LOG2E;
        Af2[j] = (float)A2;
        Sb2[j] = (float)(A2 * Rb);
    }
    float Dv = Dp[d];

    float P = 0.f;
    f32x4 Tn = {0.f, 0.f, 0.f, 0.f};
#pragma unroll 1
    for (int t4 = 0; t4 < 4; ++t4) {
        f32x4 rdv = dp[t4];
        ushort4 uv = *(const ushort4*)(up + t4 * 4);
        float ru[4] = {bf2f(uv.x), bf2f(uv.y), bf2f(uv.z), bf2f(uv.w)};
        f32x4 Bq[4];
#pragma unroll
        for (int k = 0; k < 4; ++k) Bq[k] = Bp[(t4 * 4 + k) * 4];
#pragma unroll
        for (int k = 0; k < 4; ++k) {
            float dlt = rdv[k];
            P += dlt;
            float du = dlt * ru[k];
#pragma unroll
            for (int j = 0; j < 4; ++j) {
                float e = EXP2F(fmaf(-Af2[j], P, Sb2[j]));
                Tn[j] = fmaf(du * Bq[k][j], e, Tn[j]);
            }
        }
    }
    *(f32x4*)&TcL[c * 20 + 4 * l] = Tn;
    __syncthreads();

    {
        f32x4 v = *(const f32x4*)&TcL[lane * 20 + 4 * w];
#pragma unroll
        for (int off = 1; off < 64; off <<= 1) {
            f32x4 t = shflup4(v, off);
            if (lane >= off) v += t;
        }
        f32x4 ex = shflup4(v, 1);
        if (lane == 0) ex = (f32x4){0.f, 0.f, 0.f, 0.f};
        *(f32x4*)&TcL[lane * 20 + 4 * w] = ex;
    }
    __syncthreads();
    f32x4 num = *(const f32x4*)&TcL[c * 20 + 4 * l];

    P = 0.f;
#pragma unroll 1
    for (int t4 = 0; t4 < 4; ++t4) {
        f32x4 rdv = dp[t4];
        ushort4 uv = *(const ushort4*)(up + t4 * 4);
        float ru[4] = {bf2f(uv.x), bf2f(uv.y), bf2f(uv.z), bf2f(uv.w)};
        f32x4 Bq[4], Cq[4];
#pragma unroll
        for (int k = 0; k < 4; ++k) {
            Bq[k] = Bp[(t4 * 4 + k) * 4];
            Cq[k] = Cp[(t4 * 4 + k) * 4];
        }
#pragma unroll
        for (int k = 0; k < 4; ++k) {
            float dlt = rdv[k];
            P += dlt;
            float du = dlt * ru[k];
            float psum = 0.f;
#pragma unroll
            for (int j = 0; j < 4; ++j) {
                float e = EXP2F(fmaf(-Af2[j], P, Sb2[j]));
                num[j] = fmaf(du * Bq[k][j], e, num[j]);
                float rr = __builtin_amdgcn_rcpf(e + 1e-12f);
                psum = fmaf(num[j] * rr, Cq[k][j], psum);
            }
            psum += __shfl_xor(psum, 1);
            psum += __shfl_xor(psum, 2);
            if (l == 0) syp[c * 17 + t4 * 4 + k] = fmaf(ru[k], Dv, psum);
        }
    }
    __syncthreads();
    {
        int cc = tid >> 2, oo = (tid & 3) * 4;
        const float* sp = &syp[cc * 17 + oo];
        ushort4 o;
        o.x = f2bf(sp[0]);
        o.y = f2bf(sp[1]);
        o.z = f2bf(sp[2]);
        o.w = f2bf(sp[3]);
        *reinterpret_cast<ushort4*>(&yTbf[(size_t)d * MTOT + m0 + tid * 4]) = o;
    }
}

// ---------------- yTbf [d][m] bf16 -> ybf [m][d] bf16 ----------------
__global__ __launch_bounds__(256) void k_ytr(const unsigned short* __restrict__ in,
                                             unsigned short* __restrict__ out) {
    __shared__ unsigned short t[64][66];
    int d0 = blockIdx.y * 64, m0 = blockIdx.x * 64;
    int tx = threadIdx.x & 63, ty = threadIdx.x >> 6;
#pragma unroll
    for (int j = 0; j < 64; j += 4)
        t[ty + j][tx] = in[(size_t)(d0 + ty + j) * MTOT + m0 + tx];
    __syncthreads();
#pragma unroll
    for (int j = 0; j < 64; j += 4)
        out[(size_t)(m0 + ty + j) * 1024 + d0 + tx] = t[tx][ty + j];
}

// ---------------- Kernel D: out = ybf @ WbfT^T + b_out via MFMA, BM=64, grid 512 ----------------
__global__ __launch_bounds__(256) void k_gemm(const unsigned short* __restrict__ A,
                                              const unsigned short* __restrict__ B,
                                              const float* __restrict__ bias,
                                              float* __restrict__ out) {
    __shared__ unsigned short As[64 * 64];
    __shared__ unsigned short Bs[64 * 64];
    const int GN = 1024, GK = 1024;
    int bm = blockIdx.y * 64;
    int bn = blockIdx.x * 64;
    int tid = threadIdx.x;
    int lane = tid & 63;
    int w = tid >> 6;
    int wm = w >> 1, wn = w & 1;
    int r = lane & 15, kb = lane >> 4;

    f32x4 acc[2][2];
#pragma unroll
    for (int mf = 0; mf < 2; ++mf)
#pragma unroll
        for (int nf = 0; nf < 2; ++nf) acc[mf][nf] = (f32x4){0.f, 0.f, 0.f, 0.f};

    s16x8 ra[2], rb[2];
    auto stage_load = [&](int k0) {
#pragma unroll
        for (int i = 0; i < 2; ++i) {
            int q = tid + i * 256;
            ra[i] = *reinterpret_cast<const s16x8*>(&A[(size_t)(bm + (q >> 3)) * GK + k0 + (q & 7) * 8]);
            rb[i] = *reinterpret_cast<const s16x8*>(&B[(size_t)(bn + (q >> 3)) * GK + k0 + (q & 7) * 8]);
        }
    };

    stage_load(0);
    for (int k0 = 0; k0 < GK; k0 += 64) {
        __syncthreads();
#pragma unroll
        for (int i = 0; i < 2; ++i) {
            int q = tid + i * 256;
            int row = q >> 3;
            int dstB = row * 128 + (((q & 7) * 16) ^ ((row & 7) << 4));
            *(s16x8*)((char*)As + dstB) = ra[i];
            *(s16x8*)((char*)Bs + dstB) = rb[i];
        }
        __syncthreads();
        if (k0 + 64 < GK) stage_load(k0 + 64);
#pragma unroll
        for (int ks = 0; ks < 2; ++ks) {
            int sw = (ks * 64 + kb * 16) ^ ((r & 7) << 4);
            s16x8 af[2], bfr[2];
#pragma unroll
            for (int mf = 0; mf < 2; ++mf)
                af[mf] = *(const s16x8*)((char*)As + (wm * 32 + mf * 16 + r) * 128 + sw);
#pragma unroll
            for (int nf = 0; nf < 2; ++nf)
                bfr[nf] = *(const s16x8*)((char*)Bs + (wn * 32 + nf * 16 + r) * 128 + sw);
#pragma unroll
            for (int mf = 0; mf < 2; ++mf)
#pragma unroll
                for (int nf = 0; nf < 2; ++nf)
                    acc[mf][nf] = __builtin_amdgcn_mfma_f32_16x16x32_bf16(af[mf], bfr[nf], acc[mf][nf], 0, 0, 0);
        }
    }
#pragma unroll
    for (int nf = 0; nf < 2; ++nf) {
        float bb = bias[bn + wn * 32 + nf * 16 + r];
#pragma unroll
        for (int mf = 0; mf < 2; ++mf)
#pragma unroll
            for (int j = 0; j < 4; ++j)
                out[(size_t)(bm + wm * 32 + mf * 16 + kb * 4 + j) * GN + bn + wn * 32 + nf * 16 + r] =
                    acc[mf][nf][j] + bb;
    }
}

extern "C" void kernel_launch(void* const* d_in, const int* in_sizes, int n_in,
                              void* d_out, int out_size, void* d_ws, size_t ws_size,
                              hipStream_t stream) {
    const float* x    = (const float*)d_in[0];
    const float* Wx   = (const float*)d_in[1];
    const float* Wdt  = (const float*)d_in[2];
    const float* bdt  = (const float*)d_in[3];
    const float* Alog = (const float*)d_in[4];
    const float* Dp   = (const float*)d_in[5];
    const float* Wout = (const float*)d_in[6];
    const float* bout = (const float*)d_in[7];
    float* out = (float*)d_out;

    float* deltaT = (float*)d_ws;                          // 1024*2048 f
    float* bpk    = deltaT + 1024 * 2048;                  // 2048*16 f
    float* cpk    = bpk + 2048 * 16;                       // 2048*16 f
    float* part   = cpk + 2048 * 16;                       // 4*2048*96 f
    unsigned short* xTbf  = (unsigned short*)(part + 4 * 2048 * 96);  // 1024*2048
    unsigned short* WxTh  = xTbf + 1024 * 2048;            // 96*1024
    unsigned short* WxTl  = WxTh + 96 * 1024;
    unsigned short* WdtTh = WxTl + 96 * 1024;              // 1024*64
    unsigned short* WdtTl = WdtTh + 1024 * 64;
    unsigned short* yTbf  = WdtTl + 1024 * 64;             // 1024*2048
    unsigned short* ybf   = yTbf + 1024 * 2048;            // 2048*1024
    unsigned short* WbfT  = ybf + 2048 * 1024;             // 1024*1024

    k_prep<<<928, 256, 0, stream>>>(x, Wx, Wdt, Wout, xTbf,
                                    WxTh, WxTl, WdtTh, WdtTl, WbfT);
    k_xdbl3<<<256, 256, 0, stream>>>(x, WxTh, WxTl, part);
    k_delta2<<<dim3(16, 16), 256, 0, stream>>>(part, WdtTh, WdtTl, bdt, deltaT, bpk, cpk);
    k_scan3<<<2048, 256, 0, stream>>>(deltaT, xTbf, bpk, cpk, Alog, Dp, yTbf);
    k_ytr<<<dim3(32, 16), 256, 0, stream>>>(yTbf, ybf);
    k_gemm<<<dim3(16, 32), 256, 0, stream>>>(ybf, WbfT, bout, out);
}

// Round 11
// 74.031 us; speedup vs baseline: 1.0892x; 1.0231x over previous
//
#include <hip/hip_runtime.h>
#include <hip/hip_bf16.h>

// b=2, L=1024, d=1024, dt_rank=64, n=16, E=96
#define LSEQ 1024
#define DMODEL 1024
#define NSTATE 16
#define DTRANK 64
#define ECOL 96
#define MTOT 2048

typedef short s16x8 __attribute__((ext_vector_type(8)));
typedef float f32x4 __attribute__((ext_vector_type(4)));
typedef unsigned int u32x4 __attribute__((ext_vector_type(4)));

#if __has_builtin(__builtin_amdgcn_exp2f)
#define EXP2F(x) __builtin_amdgcn_exp2f(x)
#else
#define EXP2F(x) exp2f(x)
#endif
#define LOG2E 1.4426950408889634

__device__ inline unsigned short f2bf(float f) {
    unsigned int u = __builtin_bit_cast(unsigned int, f);
    u += 0x7FFFu + ((u >> 16) & 1u);
    return (unsigned short)(u >> 16);
}
__device__ inline float bf2f(unsigned short h) {
    unsigned int u = ((unsigned int)h) << 16;
    return __builtin_bit_cast(float, u);
}

__device__ inline f32x4 shflup4(f32x4 v, int off) {
    f32x4 r;
    r[0] = __shfl_up(v[0], off, 64);
    r[1] = __shfl_up(v[1], off, 64);
    r[2] = __shfl_up(v[2], off, 64);
    r[3] = __shfl_up(v[3], off, 64);
    return r;
}

// ---------------- fused prep: x->xTbf, Wx->WxT h/l, Wdt->WdtT h/l, Wout->WbfT ----------------
__global__ __launch_bounds__(256) void k_prep(const float* __restrict__ x,
                                              const float* __restrict__ Wx,
                                              const float* __restrict__ Wdt,
                                              const float* __restrict__ Wout,
                                              unsigned short* __restrict__ xTbf,
                                              unsigned short* __restrict__ WxTh,
                                              unsigned short* __restrict__ WxTl,
                                              unsigned short* __restrict__ WdtTh,
                                              unsigned short* __restrict__ WdtTl,
                                              unsigned short* __restrict__ WbfT) {
    __shared__ float t[64][65];
    int id = blockIdx.x;
    int tid = threadIdx.x;
    if (id < 512) {
        int d0 = (id & 15) * 64, m0 = (id >> 4) * 64;
        int tx = tid & 63, ty = tid >> 6;
#pragma unroll
        for (int j = 0; j < 64; j += 4)
            t[ty + j][tx] = x[(size_t)(m0 + ty + j) * 1024 + d0 + tx];
        __syncthreads();
#pragma unroll
        for (int j = 0; j < 64; j += 4)
            xTbf[(size_t)(d0 + ty + j) * 2048 + m0 + tx] = f2bf(t[tx][ty + j]);
    } else if (id < 512 + 96) {
        int id2 = id - 512;
        int e0 = (id2 % 3) * 32, k0 = (id2 / 3) * 32;
        int tx = tid & 31, ty = tid >> 5;
#pragma unroll
        for (int j = 0; j < 32; j += 8)
            t[ty + j][tx] = Wx[(size_t)(k0 + ty + j) * 96 + e0 + tx];
        __syncthreads();
#pragma unroll
        for (int j = 0; j < 32; j += 8) {
            float v = t[tx][ty + j];
            unsigned short h = f2bf(v);
            WxTh[(size_t)(e0 + ty + j) * 1024 + k0 + tx] = h;
            WxTl[(size_t)(e0 + ty + j) * 1024 + k0 + tx] = f2bf(v - bf2f(h));
        }
    } else if (id < 512 + 96 + 64) {
        int id3 = id - (512 + 96);
        int d0 = (id3 & 31) * 32, r0 = (id3 >> 5) * 32;
        int tx = tid & 31, ty = tid >> 5;
#pragma unroll
        for (int j = 0; j < 32; j += 8)
            t[ty + j][tx] = Wdt[(size_t)(r0 + ty + j) * 1024 + d0 + tx];
        __syncthreads();
#pragma unroll
        for (int j = 0; j < 32; j += 8) {
            float v = t[tx][ty + j];
            unsigned short h = f2bf(v);
            WdtTh[(size_t)(d0 + ty + j) * 64 + r0 + tx] = h;
            WdtTl[(size_t)(d0 + ty + j) * 64 + r0 + tx] = f2bf(v - bf2f(h));
        }
    } else {
        int id4 = id - (512 + 96 + 64);
        int e0 = (id4 & 15) * 64, k0 = (id4 >> 4) * 64;
        int tx = tid & 63, ty = tid >> 6;
#pragma unroll
        for (int j = 0; j < 64; j += 4)
            t[ty + j][tx] = Wout[(size_t)(k0 + ty + j) * 1024 + e0 + tx];
        __syncthreads();
#pragma unroll
        for (int j = 0; j < 64; j += 4)
            WbfT[(size_t)(e0 + ty + j) * 1024 + k0 + tx] = f2bf(t[tx][ty + j]);
    }
}

// ---------------- xdbl via MFMA split, split-K: part[slice][2048][96] ----------------
__global__ __launch_bounds__(256) void k_xdbl3(const float* __restrict__ x,
                                               const unsigned short* __restrict__ WxTh,
                                               const unsigned short* __restrict__ WxTl,
                                               float* __restrict__ part) {
    __shared__ unsigned short Ah[32 * 64], Al[32 * 64];
    __shared__ unsigned short Bh[96 * 64], Bl[96 * 64];
    int bm = (blockIdx.x >> 2) * 32;
    int slice = blockIdx.x & 3;
    int tid = threadIdx.x, lane = tid & 63, w = tid >> 6;
    int wm = w >> 1, wn = w & 1;
    int r = lane & 15, kb = lane >> 4;

    f32x4 acc[3];
#pragma unroll
    for (int nf = 0; nf < 3; ++nf) acc[nf] = (f32x4){0.f, 0.f, 0.f, 0.f};

#pragma unroll 1
    for (int kc = 0; kc < 4; ++kc) {
        int kbase = slice * 256 + kc * 64;
        __syncthreads();
        {
            int row = tid >> 3, cc = tid & 7;
            size_t src = (size_t)(bm + row) * 1024 + kbase + cc * 8;
            float4 v0 = *(const float4*)&x[src];
            float4 v1 = *(const float4*)&x[src + 4];
            float vv[8] = {v0.x, v0.y, v0.z, v0.w, v1.x, v1.y, v1.z, v1.w};
            s16x8 h, lo;
#pragma unroll
            for (int j = 0; j < 8; ++j) {
                unsigned short hb = f2bf(vv[j]);
                h[j] = (short)hb;
                lo[j] = (short)f2bf(vv[j] - bf2f(hb));
            }
            int dstB = row * 128 + ((cc * 16) ^ ((row & 7) << 4));
            *(s16x8*)((char*)Ah + dstB) = h;
            *(s16x8*)((char*)Al + dstB) = lo;
        }
#pragma unroll
        for (int j = 0; j < 3; ++j) {
            int c = tid + j * 256;
            int row = c >> 3, cc = c & 7;
            size_t src = (size_t)row * 1024 + kbase + cc * 8;
            int dstB = row * 128 + ((cc * 16) ^ ((row & 7) << 4));
            *(s16x8*)((char*)Bh + dstB) = *(const s16x8*)&WxTh[src];
            *(s16x8*)((char*)Bl + dstB) = *(const s16x8*)&WxTl[src];
        }
        __syncthreads();
#pragma unroll
        for (int ks = 0; ks < 2; ++ks) {
            int sw = (ks * 64 + kb * 16) ^ ((r & 7) << 4);
            s16x8 a_h = *(const s16x8*)((char*)Ah + (wm * 16 + r) * 128 + sw);
            s16x8 a_l = *(const s16x8*)((char*)Al + (wm * 16 + r) * 128 + sw);
#pragma unroll
            for (int nf = 0; nf < 3; ++nf) {
                int brow = wn * 48 + nf * 16 + r;
                s16x8 b_h = *(const s16x8*)((char*)Bh + brow * 128 + sw);
                s16x8 b_l = *(const s16x8*)((char*)Bl + brow * 128 + sw);
                acc[nf] = __builtin_amdgcn_mfma_f32_16x16x32_bf16(a_h, b_h, acc[nf], 0, 0, 0);
                acc[nf] = __builtin_amdgcn_mfma_f32_16x16x32_bf16(a_h, b_l, acc[nf], 0, 0, 0);
                acc[nf] = __builtin_amdgcn_mfma_f32_16x16x32_bf16(a_l, b_h, acc[nf], 0, 0, 0);
            }
        }
    }
    float* pb = part + (size_t)slice * 2048 * 96;
#pragma unroll
    for (int nf = 0; nf < 3; ++nf)
#pragma unroll
        for (int j = 0; j < 4; ++j)
            pb[(size_t)(bm + wm * 16 + kb * 4 + j) * 96 + wn * 48 + nf * 16 + r] = acc[nf][j];
}

// ---------------- delta via MFMA (fused part-reduce): M-tile 128, N-tile 64, K=64 ----------------
__global__ __launch_bounds__(256) void k_delta2(const float* __restrict__ part,
                                                const unsigned short* __restrict__ WdtTh,
                                                const unsigned short* __restrict__ WdtTl,
                                                const float* __restrict__ bdt,
                                                float* __restrict__ deltaT,
                                                float* __restrict__ bpk,
                                                float* __restrict__ cpk) {
    __shared__ char pool[34816];
    unsigned short* Ah = (unsigned short*)pool;
    unsigned short* Al = (unsigned short*)(pool + 16384);
    float (*slab)[32][68] = (float (*)[32][68])pool;

    int bm = blockIdx.y * 128;
    int bn = blockIdx.x * 64;
    int tid = threadIdx.x, lane = tid & 63, w = tid >> 6;
    int wm = w >> 1, wn = w & 1;
    int r = lane & 15, kb = lane >> 4;

#pragma unroll
    for (int i = 0; i < 8; ++i) {
        int q = tid + i * 256;
        int row = q >> 4, c4 = q & 15;
        size_t off = (size_t)(bm + row) * 96 + c4 * 4;
        f32x4 v = *(const f32x4*)&part[off];
#pragma unroll
        for (int s = 1; s < 4; ++s) v += *(const f32x4*)&part[(size_t)s * 2048 * 96 + off];
        ushort4 h4, l4;
        h4.x = f2bf(v[0]); l4.x = f2bf(v[0] - bf2f(h4.x));
        h4.y = f2bf(v[1]); l4.y = f2bf(v[1] - bf2f(h4.y));
        h4.z = f2bf(v[2]); l4.z = f2bf(v[2] - bf2f(h4.z));
        h4.w = f2bf(v[3]); l4.w = f2bf(v[3] - bf2f(h4.w));
        int dstB = row * 128 + ((c4 * 8) ^ ((row & 7) << 4));
        *(ushort4*)((char*)Ah + dstB) = h4;
        *(ushort4*)((char*)Al + dstB) = l4;
    }
    if (blockIdx.x == 0) {
#pragma unroll
        for (int i = 0; i < 4; ++i) {
            int q = tid + i * 256;
            int row = q >> 3, c4 = q & 7;
            size_t off = (size_t)(bm + row) * 96 + 64 + c4 * 4;
            f32x4 v = *(const f32x4*)&part[off];
#pragma unroll
            for (int s = 1; s < 4; ++s) v += *(const f32x4*)&part[(size_t)s * 2048 * 96 + off];
            if (c4 < 4) *(f32x4*)&bpk[(size_t)(bm + row) * 16 + c4 * 4] = v;
            else        *(f32x4*)&cpk[(size_t)(bm + row) * 16 + (c4 - 4) * 4] = v;
        }
    }
    __syncthreads();

    f32x4 acc[4][2];
#pragma unroll
    for (int mf = 0; mf < 4; ++mf)
#pragma unroll
        for (int nf = 0; nf < 2; ++nf) acc[mf][nf] = (f32x4){0.f, 0.f, 0.f, 0.f};

#pragma unroll
    for (int ks = 0; ks < 2; ++ks) {
        int sw = (ks * 64 + kb * 16) ^ ((r & 7) << 4);
        s16x8 Afh[4], Afl[4], Bh[2], Bl[2];
#pragma unroll
        for (int mf = 0; mf < 4; ++mf) {
            int arow = wm * 64 + mf * 16 + r;
            Afh[mf] = *(const s16x8*)((char*)Ah + arow * 128 + sw);
            Afl[mf] = *(const s16x8*)((char*)Al + arow * 128 + sw);
        }
#pragma unroll
        for (int nf = 0; nf < 2; ++nf) {
            size_t b = (size_t)(bn + wn * 32 + nf * 16 + r) * 64 + ks * 32 + kb * 8;
            Bh[nf] = *(const s16x8*)&WdtTh[b];
            Bl[nf] = *(const s16x8*)&WdtTl[b];
        }
#pragma unroll
        for (int mf = 0; mf < 4; ++mf)
#pragma unroll
            for (int nf = 0; nf < 2; ++nf) {
                acc[mf][nf] = __builtin_amdgcn_mfma_f32_16x16x32_bf16(Afh[mf], Bh[nf], acc[mf][nf], 0, 0, 0);
                acc[mf][nf] = __builtin_amdgcn_mfma_f32_16x16x32_bf16(Afh[mf], Bl[nf], acc[mf][nf], 0, 0, 0);
                acc[mf][nf] = __builtin_amdgcn_mfma_f32_16x16x32_bf16(Afl[mf], Bh[nf], acc[mf][nf], 0, 0, 0);
            }
    }
    __syncthreads();

#pragma unroll
    for (int nf = 0; nf < 2; ++nf) {
        float bb = bdt[bn + wn * 32 + nf * 16 + r];
#pragma unroll
        for (int mf = 0; mf < 4; ++mf)
#pragma unroll
            for (int j = 0; j < 4; ++j) {
                float z = acc[mf][nf][j] + bb;
                float sp = fmaxf(z, 0.f) + log1pf(expf(-fabsf(z)));
                slab[w][nf * 16 + r][mf * 16 + kb * 4 + j] = sp;
            }
    }
#pragma unroll
    for (int i = 0; i < 8; ++i) {
        int idx = i * 64 + lane;
        int dl = idx >> 4, mq = (idx & 15) * 4;
        f32x4 v = *(const f32x4*)&slab[w][dl][mq];
        *(f32x4*)&deltaT[(size_t)(bn + wn * 32 + dl) * MTOT + bm + wm * 64 + mq] = v;
    }
}

// ---------------- Kernel C: chunked selective scan (single-d, bf16 u, base-2 exp) ----------------
__global__ __launch_bounds__(256) void k_scan3(const float* __restrict__ deltaT,
                                               const unsigned short* __restrict__ xTbf,
                                               const float* __restrict__ bpk,
                                               const float* __restrict__ cpk,
                                               const float* __restrict__ Alog,
                                               const float* __restrict__ Dp,
                                               unsigned short* __restrict__ yTbf) {
    __shared__ double csum[64];
    __shared__ double Rbef[64];
    __shared__ float TcL[64 * 20];
    __shared__ float syp[64 * 17];

    int tid = threadIdx.x;
    int c = tid >> 2, l = tid & 3;
    int w = tid >> 6, lane = tid & 63;
    int d = blockIdx.x & 1023, b = blockIdx.x >> 10;
    int m0 = b * 1024;

    const f32x4* dp = (const f32x4*)(deltaT + (size_t)d * MTOT + m0 + c * 16);
    const unsigned short* up = xTbf + (size_t)d * MTOT + m0 + c * 16;
    const f32x4* Bp = (const f32x4*)bpk + (size_t)(m0 + c * 16) * 4 + l;
    const f32x4* Cp = (const f32x4*)cpk + (size_t)(m0 + c * 16) * 4 + l;

    double dsum = 0.0;
#pragma unroll
    for (int i = 0; i < 4; ++i) {
        f32x4 v = dp[i];
        dsum += (double)v[0] + (double)v[1] + (double)v[2] + (double)v[3];
    }
    if (l == 0) csum[c] = dsum;
    __syncthreads();
    if (tid < 64) {
        double v = csum[tid];
#pragma unroll
        for (int off = 1; off < 64; off <<= 1) {
            double t = __shfl_down(v, off, 64);
            if (tid + off < 64) v += t;
        }
        Rbef[tid] = v;
    }
    __syncthreads();

    float Af2[4], Sb2[4];
    double Rb = Rbef[c];
#pragma unroll
    for (int j = 0; j < 4; ++j) {
        float Af = -__expf(Alog[d * NSTATE + 4 * l + j]);
        double A2 = (double)Af * LOG2E;
        Af2[j] = (float)A2;
        Sb2[j] = (float)(A2 * Rb);
    }
    float Dv = Dp[d];

    float P = 0.f;
    f32x4 Tn = {0.f, 0.f, 0.f, 0.f};
#pragma unroll 1
    for (int t4 = 0; t4 < 4; ++t4) {
        f32x4 rdv = dp[t4];
        ushort4 uv = *(const ushort4*)(up + t4 * 4);
        float ru[4] = {bf2f(uv.x), bf2f(uv.y), bf2f(uv.z), bf2f(uv.w)};
        f32x4 Bq[4];
#pragma unroll
        for (int k = 0; k < 4; ++k) Bq[k] = Bp[(t4 * 4 + k) * 4];
#pragma unroll
        for (int k = 0; k < 4; ++k) {
            float dlt = rdv[k];
            P += dlt;
            float du = dlt * ru[k];
#pragma unroll
            for (int j = 0; j < 4; ++j) {
                float e = EXP2F(fmaf(-Af2[j], P, Sb2[j]));
                Tn[j] = fmaf(du * Bq[k][j], e, Tn[j]);
            }
        }
    }
    *(f32x4*)&TcL[c * 20 + 4 * l] = Tn;
    __syncthreads();

    {
        f32x4 v = *(const f32x4*)&TcL[lane * 20 + 4 * w];
#pragma unroll
        for (int off = 1; off < 64; off <<= 1) {
            f32x4 t = shflup4(v, off);
            if (lane >= off) v += t;
        }
        f32x4 ex = shflup4(v, 1);
        if (lane == 0) ex = (f32x4){0.f, 0.f, 0.f, 0.f};
        *(f32x4*)&TcL[lane * 20 + 4 * w] = ex;
    }
    __syncthreads();
    f32x4 num = *(const f32x4*)&TcL[c * 20 + 4 * l];

    P = 0.f;
#pragma unroll 1
    for (int t4 = 0; t4 < 4; ++t4) {
        f32x4 rdv = dp[t4];
        ushort4 uv = *(const ushort4*)(up + t4 * 4);
        float ru[4] = {bf2f(uv.x), bf2f(uv.y), bf2f(uv.z), bf2f(uv.w)};
        f32x4 Bq[4], Cq[4];
#pragma unroll
        for (int k = 0; k < 4; ++k) {
            Bq[k] = Bp[(t4 * 4 + k) * 4];
            Cq[k] = Cp[(t4 * 4 + k) * 4];
        }
#pragma unroll
        for (int k = 0; k < 4; ++k) {
            float dlt = rdv[k];
            P += dlt;
            float du = dlt * ru[k];
            float psum = 0.f;
#pragma unroll
            for (int j = 0; j < 4; ++j) {
                float e = EXP2F(fmaf(-Af2[j], P, Sb2[j]));
                num[j] = fmaf(du * Bq[k][j], e, num[j]);
                float rr = __builtin_amdgcn_rcpf(e + 1e-12f);
                psum = fmaf(num[j] * rr, Cq[k][j], psum);
            }
            psum += __shfl_xor(psum, 1);
            psum += __shfl_xor(psum, 2);
            if (l == 0) syp[c * 17 + t4 * 4 + k] = fmaf(ru[k], Dv, psum);
        }
    }
    __syncthreads();
    {
        int cc = tid >> 2, oo = (tid & 3) * 4;
        const float* sp = &syp[cc * 17 + oo];
        ushort4 o;
        o.x = f2bf(sp[0]);
        o.y = f2bf(sp[1]);
        o.z = f2bf(sp[2]);
        o.w = f2bf(sp[3]);
        *reinterpret_cast<ushort4*>(&yTbf[(size_t)d * MTOT + m0 + tid * 4]) = o;
    }
}

// ---------------- Kernel D: out = y @ Wout^T... A staged DIRECTLY from yTbf [d][m] ----------------
// A-tile transpose via u32 pair-packing: P[p][m] = y[2p][m] | y[2p+1][m]<<16
// (one u32 == one MFMA A-frag dword, since frags pack k-pairs per dword)
__global__ __launch_bounds__(256) void k_gemm(const unsigned short* __restrict__ yT,
                                              const unsigned short* __restrict__ B,
                                              const float* __restrict__ bias,
                                              float* __restrict__ out) {
    __shared__ unsigned int P[32 * 68];      // pair-rows x m, stride 68 (2-way banks only)
    __shared__ unsigned short Bs[64 * 64];
    const int GN = 1024, GK = 1024;
    int bm = blockIdx.y * 64;
    int bn = blockIdx.x * 64;
    int tid = threadIdx.x;
    int lane = tid & 63;
    int w = tid >> 6;
    int wm = w >> 1, wn = w & 1;
    int r = lane & 15, kb = lane >> 4;

    f32x4 acc[2][2];
#pragma unroll
    for (int mf = 0; mf < 2; ++mf)
#pragma unroll
        for (int nf = 0; nf < 2; ++nf) acc[mf][nf] = (f32x4){0.f, 0.f, 0.f, 0.f};

    ushort4 rya[2], ryb[2];
    s16x8 rbv[2];
    auto stage_load = [&](int k0) {
#pragma unroll
        for (int i = 0; i < 2; ++i) {
            int slot = tid + i * 256;
            int p = slot >> 4, mq = (slot & 15) * 4;
            rya[i] = *(const ushort4*)&yT[(size_t)(k0 + 2 * p) * MTOT + bm + mq];
            ryb[i] = *(const ushort4*)&yT[(size_t)(k0 + 2 * p + 1) * MTOT + bm + mq];
            rbv[i] = *(const s16x8*)&B[(size_t)(bn + (slot >> 3)) * GK + k0 + (slot & 7) * 8];
        }
    };

    stage_load(0);
    for (int k0 = 0; k0 < GK; k0 += 64) {
        __syncthreads();
#pragma unroll
        for (int i = 0; i < 2; ++i) {
            int slot = tid + i * 256;
            int p = slot >> 4, mq = (slot & 15) * 4;
            u32x4 pk;
            pk[0] = (unsigned int)rya[i].x | ((unsigned int)ryb[i].x << 16);
            pk[1] = (unsigned int)rya[i].y | ((unsigned int)ryb[i].y << 16);
            pk[2] = (unsigned int)rya[i].z | ((unsigned int)ryb[i].z << 16);
            pk[3] = (unsigned int)rya[i].w | ((unsigned int)ryb[i].w << 16);
            *(u32x4*)&P[p * 68 + mq] = pk;
            int row = slot >> 3;
            int dstB = row * 128 + (((slot & 7) * 16) ^ ((row & 7) << 4));
            *(s16x8*)((char*)Bs + dstB) = rbv[i];
        }
        __syncthreads();
        if (k0 + 64 < GK) stage_load(k0 + 64);
#pragma unroll
        for (int ks = 0; ks < 2; ++ks) {
            int sw = (ks * 64 + kb * 16) ^ ((r & 7) << 4);
            s16x8 af[2], bfr[2];
#pragma unroll
            for (int mf = 0; mf < 2; ++mf) {
                int base = (ks * 16 + kb * 4) * 68 + wm * 32 + mf * 16 + r;
                u32x4 av;
                av[0] = P[base];
                av[1] = P[base + 68];
                av[2] = P[base + 136];
                av[3] = P[base + 204];
                af[mf] = __builtin_bit_cast(s16x8, av);
            }
#pragma unroll
            for (int nf = 0; nf < 2; ++nf)
                bfr[nf] = *(const s16x8*)((char*)Bs + (wn * 32 + nf * 16 + r) * 128 + sw);
#pragma unroll
            for (int mf = 0; mf < 2; ++mf)
#pragma unroll
                for (int nf = 0; nf < 2; ++nf)
                    acc[mf][nf] = __builtin_amdgcn_mfma_f32_16x16x32_bf16(af[mf], bfr[nf], acc[mf][nf], 0, 0, 0);
        }
    }
#pragma unroll
    for (int nf = 0; nf < 2; ++nf) {
        float bb = bias[bn + wn * 32 + nf * 16 + r];
#pragma unroll
        for (int mf = 0; mf < 2; ++mf)
#pragma unroll
            for (int j = 0; j < 4; ++j)
                out[(size_t)(bm + wm * 32 + mf * 16 + kb * 4 + j) * GN + bn + wn * 32 + nf * 16 + r] =
                    acc[mf][nf][j] + bb;
    }
}

extern "C" void kernel_launch(void* const* d_in, const int* in_sizes, int n_in,
                              void* d_out, int out_size, void* d_ws, size_t ws_size,
                              hipStream_t stream) {
    const float* x    = (const float*)d_in[0];
    const float* Wx   = (const float*)d_in[1];
    const float* Wdt  = (const float*)d_in[2];
    const float* bdt  = (const float*)d_in[3];
    const float* Alog = (const float*)d_in[4];
    const float* Dp   = (const float*)d_in[5];
    const float* Wout = (const float*)d_in[6];
    const float* bout = (const float*)d_in[7];
    float* out = (float*)d_out;

    float* deltaT = (float*)d_ws;                          // 1024*2048 f
    float* bpk    = deltaT + 1024 * 2048;                  // 2048*16 f
    float* cpk    = bpk + 2048 * 16;                       // 2048*16 f
    float* part   = cpk + 2048 * 16;                       // 4*2048*96 f
    unsigned short* xTbf  = (unsigned short*)(part + 4 * 2048 * 96);  // 1024*2048
    unsigned short* WxTh  = xTbf + 1024 * 2048;            // 96*1024
    unsigned short* WxTl  = WxTh + 96 * 1024;
    unsigned short* WdtTh = WxTl + 96 * 1024;              // 1024*64
    unsigned short* WdtTl = WdtTh + 1024 * 64;
    unsigned short* yTbf  = WdtTl + 1024 * 64;             // 1024*2048
    unsigned short* WbfT  = yTbf + 1024 * 2048;            // 1024*1024

    k_prep<<<928, 256, 0, stream>>>(x, Wx, Wdt, Wout, xTbf,
                                    WxTh, WxTl, WdtTh, WdtTl, WbfT);
    k_xdbl3<<<256, 256, 0, stream>>>(x, WxTh, WxTl, part);
    k_delta2<<<dim3(16, 16), 256, 0, stream>>>(part, WdtTh, WdtTl, bdt, deltaT, bpk, cpk);
    k_scan3<<<2048, 256, 0, stream>>>(deltaT, xTbf, bpk, cpk, Alog, Dp, yTbf);
    k_gemm<<<dim3(16, 32), 256, 0, stream>>>(yTbf, WbfT, bout, out);
}

// Round 13
// 65.471 us; speedup vs baseline: 1.2316x; 1.1308x over previous
//
#include <hip/hip_runtime.h>
#include <hip/hip_bf16.h>

// b=2, L=1024, d=1024, dt_rank=64, n=16, E=96
#define LSEQ 1024
#define DMODEL 1024
#define NSTATE 16
#define DTRANK 64
#define ECOL 96
#define MTOT 2048

typedef short s16x8 __attribute__((ext_vector_type(8)));
typedef float f32x4 __attribute__((ext_vector_type(4)));
typedef unsigned int u32x4 __attribute__((ext_vector_type(4)));

#if __has_builtin(__builtin_amdgcn_exp2f)
#define EXP2F(x) __builtin_amdgcn_exp2f(x)
#else
#define EXP2F(x) exp2f(x)
#endif
#define LOG2E 1.4426950408889634

__device__ inline unsigned short f2bf(float f) {
    unsigned int u = __builtin_bit_cast(unsigned int, f);
    u += 0x7FFFu + ((u >> 16) & 1u);
    return (unsigned short)(u >> 16);
}
__device__ inline float bf2f(unsigned short h) {
    unsigned int u = ((unsigned int)h) << 16;
    return __builtin_bit_cast(float, u);
}

__device__ inline f32x4 shflup4(f32x4 v, int off) {
    f32x4 r;
    r[0] = __shfl_up(v[0], off, 64);
    r[1] = __shfl_up(v[1], off, 64);
    r[2] = __shfl_up(v[2], off, 64);
    r[3] = __shfl_up(v[3], off, 64);
    return r;
}

// ============ Kernel 1: xdbl split-K MFMA (256 vb) + WdtT riders (64) + WbfT riders (256) ============
// compute blocks convert Wx fp32 -> bf16 h/l swizzled LDS on the fly (no WxT buffer)
__global__ __launch_bounds__(256) void k_xdbl(const float* __restrict__ x,
                                              const float* __restrict__ Wx,
                                              const float* __restrict__ Wdt,
                                              const float* __restrict__ Wout,
                                              float* __restrict__ part,
                                              unsigned short* __restrict__ WdtTh,
                                              unsigned short* __restrict__ WdtTl,
                                              unsigned short* __restrict__ WbfT) {
    __shared__ alignas(16) char pool[32768];
    int bid = blockIdx.x;
    int tid = threadIdx.x;

    if (bid >= 256) {
        float (*t)[65] = (float (*)[65])pool;
        if (bid < 320) {  // WdtT: Wdt [64][1024] -> [d][r] bf16 h/l
            int id3 = bid - 256;
            int d0 = (id3 & 31) * 32, r0 = (id3 >> 5) * 32;
            int tx = tid & 31, ty = tid >> 5;
#pragma unroll
            for (int j = 0; j < 32; j += 8)
                t[ty + j][tx] = Wdt[(size_t)(r0 + ty + j) * 1024 + d0 + tx];
            __syncthreads();
#pragma unroll
            for (int j = 0; j < 32; j += 8) {
                float v = t[tx][ty + j];
                unsigned short h = f2bf(v);
                WdtTh[(size_t)(d0 + ty + j) * 64 + r0 + tx] = h;
                WdtTl[(size_t)(d0 + ty + j) * 64 + r0 + tx] = f2bf(v - bf2f(h));
            }
        } else {          // WbfT: Wout [k][e] -> [e][k] bf16
            int id4 = bid - 320;
            int e0 = (id4 & 15) * 64, k0 = (id4 >> 4) * 64;
            int tx = tid & 63, ty = tid >> 6;
#pragma unroll
            for (int j = 0; j < 64; j += 4)
                t[ty + j][tx] = Wout[(size_t)(k0 + ty + j) * 1024 + e0 + tx];
            __syncthreads();
#pragma unroll
            for (int j = 0; j < 64; j += 4)
                WbfT[(size_t)(e0 + ty + j) * 1024 + k0 + tx] = f2bf(t[tx][ty + j]);
        }
        return;
    }

    unsigned short* Ah = (unsigned short*)pool;
    unsigned short* Al = (unsigned short*)(pool + 4096);
    unsigned short* Bh = (unsigned short*)(pool + 8192);
    unsigned short* Bl = (unsigned short*)(pool + 20480);
    int bm = (bid >> 2) * 32;
    int slice = bid & 3;
    int lane = tid & 63, w = tid >> 6;
    int wm = w >> 1, wn = w & 1;
    int r = lane & 15, kb = lane >> 4;

    f32x4 acc[3];
#pragma unroll
    for (int nf = 0; nf < 3; ++nf) acc[nf] = (f32x4){0.f, 0.f, 0.f, 0.f};

#pragma unroll 1
    for (int kc = 0; kc < 4; ++kc) {
        int kbase = slice * 256 + kc * 64;
        __syncthreads();
        {   // stage A: x fp32 -> h/l regs -> swizzled LDS
            int row = tid >> 3, cc = tid & 7;
            size_t src = (size_t)(bm + row) * 1024 + kbase + cc * 8;
            float4 v0 = *(const float4*)&x[src];
            float4 v1 = *(const float4*)&x[src + 4];
            float vv[8] = {v0.x, v0.y, v0.z, v0.w, v1.x, v1.y, v1.z, v1.w};
            s16x8 h, lo;
#pragma unroll
            for (int j = 0; j < 8; ++j) {
                unsigned short hb = f2bf(vv[j]);
                h[j] = (short)hb;
                lo[j] = (short)f2bf(vv[j] - bf2f(hb));
            }
            int dstB = row * 128 + ((cc * 16) ^ ((row & 7) << 4));
            *(s16x8*)((char*)Ah + dstB) = h;
            *(s16x8*)((char*)Al + dstB) = lo;
        }
        // stage B: Wx [k][96] fp32 -> transpose+split -> swizzled LDS [e][k] h/l
#pragma unroll
        for (int it = 0; it < 3; ++it) {
            int item = it * 256 + tid;   // 0..767 = 96 e x 8 cc
            int e = item % 96;
            int cc = item / 96;
            s16x8 h, lo;
#pragma unroll
            for (int j = 0; j < 8; ++j) {
                float v = Wx[(size_t)(kbase + cc * 8 + j) * 96 + e];
                unsigned short hb = f2bf(v);
                h[j] = (short)hb;
                lo[j] = (short)f2bf(v - bf2f(hb));
            }
            int dstB = e * 128 + ((cc * 16) ^ ((e & 7) << 4));
            *(s16x8*)((char*)Bh + dstB) = h;
            *(s16x8*)((char*)Bl + dstB) = lo;
        }
        __syncthreads();
#pragma unroll
        for (int ks = 0; ks < 2; ++ks) {
            int sw = (ks * 64 + kb * 16) ^ ((r & 7) << 4);
            s16x8 a_h = *(const s16x8*)((char*)Ah + (wm * 16 + r) * 128 + sw);
            s16x8 a_l = *(const s16x8*)((char*)Al + (wm * 16 + r) * 128 + sw);
#pragma unroll
            for (int nf = 0; nf < 3; ++nf) {
                int brow = wn * 48 + nf * 16 + r;
                s16x8 b_h = *(const s16x8*)((char*)Bh + brow * 128 + sw);
                s16x8 b_l = *(const s16x8*)((char*)Bl + brow * 128 + sw);
                acc[nf] = __builtin_amdgcn_mfma_f32_16x16x32_bf16(a_h, b_h, acc[nf], 0, 0, 0);
                acc[nf] = __builtin_amdgcn_mfma_f32_16x16x32_bf16(a_h, b_l, acc[nf], 0, 0, 0);
                acc[nf] = __builtin_amdgcn_mfma_f32_16x16x32_bf16(a_l, b_h, acc[nf], 0, 0, 0);
            }
        }
    }
    float* pb = part + (size_t)slice * 2048 * 96;
#pragma unroll
    for (int nf = 0; nf < 3; ++nf)
#pragma unroll
        for (int j = 0; j < 4; ++j)
            pb[(size_t)(bm + wm * 16 + kb * 4 + j) * 96 + wn * 48 + nf * 16 + r] = acc[nf][j];
}

// ============ Kernel 2: delta2 (256 vb) + x->xTbf transpose riders (512) ============
__global__ __launch_bounds__(256) void k_delta2(const float* __restrict__ part,
                                                const unsigned short* __restrict__ WdtTh,
                                                const unsigned short* __restrict__ WdtTl,
                                                const float* __restrict__ bdt,
                                                const float* __restrict__ x,
                                                float* __restrict__ deltaT,
                                                float* __restrict__ bpk,
                                                float* __restrict__ cpk,
                                                unsigned short* __restrict__ xTbf) {
    __shared__ alignas(16) char pool[34816];
    int bid = blockIdx.x;
    int tid = threadIdx.x;

    if (bid >= 256) {  // rider: x [m][d] fp32 -> xTbf [d][m] bf16
        float (*t)[65] = (float (*)[65])pool;
        int id = bid - 256;
        int d0 = (id & 15) * 64, m0 = (id >> 4) * 64;
        int tx = tid & 63, ty = tid >> 6;
#pragma unroll
        for (int j = 0; j < 64; j += 4)
            t[ty + j][tx] = x[(size_t)(m0 + ty + j) * 1024 + d0 + tx];
        __syncthreads();
#pragma unroll
        for (int j = 0; j < 64; j += 4)
            xTbf[(size_t)(d0 + ty + j) * 2048 + m0 + tx] = f2bf(t[tx][ty + j]);
        return;
    }

    unsigned short* Ah = (unsigned short*)pool;
    unsigned short* Al = (unsigned short*)(pool + 16384);
    float (*slab)[32][68] = (float (*)[32][68])pool;
    int bxq = bid & 15, byq = bid >> 4;
    int bm = byq * 128;
    int bn = bxq * 64;
    int lane = tid & 63, w = tid >> 6;
    int wm = w >> 1, wn = w & 1;
    int r = lane & 15, kb = lane >> 4;

#pragma unroll
    for (int i = 0; i < 8; ++i) {
        int q = tid + i * 256;
        int row = q >> 4, c4 = q & 15;
        size_t off = (size_t)(bm + row) * 96 + c4 * 4;
        f32x4 v = *(const f32x4*)&part[off];
#pragma unroll
        for (int s = 1; s < 4; ++s) v += *(const f32x4*)&part[(size_t)s * 2048 * 96 + off];
        ushort4 h4, l4;
        h4.x = f2bf(v[0]); l4.x = f2bf(v[0] - bf2f(h4.x));
        h4.y = f2bf(v[1]); l4.y = f2bf(v[1] - bf2f(h4.y));
        h4.z = f2bf(v[2]); l4.z = f2bf(v[2] - bf2f(h4.z));
        h4.w = f2bf(v[3]); l4.w = f2bf(v[3] - bf2f(h4.w));
        int dstB = row * 128 + ((c4 * 8) ^ ((row & 7) << 4));
        *(ushort4*)((char*)Ah + dstB) = h4;
        *(ushort4*)((char*)Al + dstB) = l4;
    }
    if (bxq == 0) {
#pragma unroll
        for (int i = 0; i < 4; ++i) {
            int q = tid + i * 256;
            int row = q >> 3, c4 = q & 7;
            size_t off = (size_t)(bm + row) * 96 + 64 + c4 * 4;
            f32x4 v = *(const f32x4*)&part[off];
#pragma unroll
            for (int s = 1; s < 4; ++s) v += *(const f32x4*)&part[(size_t)s * 2048 * 96 + off];
            if (c4 < 4) *(f32x4*)&bpk[(size_t)(bm + row) * 16 + c4 * 4] = v;
            else        *(f32x4*)&cpk[(size_t)(bm + row) * 16 + (c4 - 4) * 4] = v;
        }
    }
    __syncthreads();

    f32x4 acc[4][2];
#pragma unroll
    for (int mf = 0; mf < 4; ++mf)
#pragma unroll
        for (int nf = 0; nf < 2; ++nf) acc[mf][nf] = (f32x4){0.f, 0.f, 0.f, 0.f};

#pragma unroll
    for (int ks = 0; ks < 2; ++ks) {
        int sw = (ks * 64 + kb * 16) ^ ((r & 7) << 4);
        s16x8 Afh[4], Afl[4], Bh[2], Bl[2];
#pragma unroll
        for (int mf = 0; mf < 4; ++mf) {
            int arow = wm * 64 + mf * 16 + r;
            Afh[mf] = *(const s16x8*)((char*)Ah + arow * 128 + sw);
            Afl[mf] = *(const s16x8*)((char*)Al + arow * 128 + sw);
        }
#pragma unroll
        for (int nf = 0; nf < 2; ++nf) {
            size_t b = (size_t)(bn + wn * 32 + nf * 16 + r) * 64 + ks * 32 + kb * 8;
            Bh[nf] = *(const s16x8*)&WdtTh[b];
            Bl[nf] = *(const s16x8*)&WdtTl[b];
        }
#pragma unroll
        for (int mf = 0; mf < 4; ++mf)
#pragma unroll
            for (int nf = 0; nf < 2; ++nf) {
                acc[mf][nf] = __builtin_amdgcn_mfma_f32_16x16x32_bf16(Afh[mf], Bh[nf], acc[mf][nf], 0, 0, 0);
                acc[mf][nf] = __builtin_amdgcn_mfma_f32_16x16x32_bf16(Afh[mf], Bl[nf], acc[mf][nf], 0, 0, 0);
                acc[mf][nf] = __builtin_amdgcn_mfma_f32_16x16x32_bf16(Afl[mf], Bh[nf], acc[mf][nf], 0, 0, 0);
            }
    }
    __syncthreads();

#pragma unroll
    for (int nf = 0; nf < 2; ++nf) {
        float bb = bdt[bn + wn * 32 + nf * 16 + r];
#pragma unroll
        for (int mf = 0; mf < 4; ++mf)
#pragma unroll
            for (int j = 0; j < 4; ++j) {
                float z = acc[mf][nf][j] + bb;
                float sp = fmaxf(z, 0.f) + log1pf(expf(-fabsf(z)));
                slab[w][nf * 16 + r][mf * 16 + kb * 4 + j] = sp;
            }
    }
#pragma unroll
    for (int i = 0; i < 8; ++i) {
        int idx = i * 64 + lane;
        int dl = idx >> 4, mq = (idx & 15) * 4;
        f32x4 v = *(const f32x4*)&slab[w][dl][mq];
        *(f32x4*)&deltaT[(size_t)(bn + wn * 32 + dl) * MTOT + bm + wm * 64 + mq] = v;
    }
}

// ---------------- Kernel 3: chunked selective scan (single-d, bf16 u, base-2 exp) ----------------
__global__ __launch_bounds__(256) void k_scan3(const float* __restrict__ deltaT,
                                               const unsigned short* __restrict__ xTbf,
                                               const float* __restrict__ bpk,
                                               const float* __restrict__ cpk,
                                               const float* __restrict__ Alog,
                                               const float* __restrict__ Dp,
                                               unsigned short* __restrict__ yTbf) {
    __shared__ double csum[64];
    __shared__ double Rbef[64];
    __shared__ float TcL[64 * 20];
    __shared__ float syp[64 * 17];

    int tid = threadIdx.x;
    int c = tid >> 2, l = tid & 3;
    int w = tid >> 6, lane = tid & 63;
    int d = blockIdx.x & 1023, b = blockIdx.x >> 10;
    int m0 = b * 1024;

    const f32x4* dp = (const f32x4*)(deltaT + (size_t)d * MTOT + m0 + c * 16);
    const unsigned short* up = xTbf + (size_t)d * MTOT + m0 + c * 16;
    const f32x4* Bp = (const f32x4*)bpk + (size_t)(m0 + c * 16) * 4 + l;
    const f32x4* Cp = (const f32x4*)cpk + (size_t)(m0 + c * 16) * 4 + l;

    double dsum = 0.0;
#pragma unroll
    for (int i = 0; i < 4; ++i) {
        f32x4 v = dp[i];
        dsum += (double)v[0] + (double)v[1] + (double)v[2] + (double)v[3];
    }
    if (l == 0) csum[c] = dsum;
    __syncthreads();
    if (tid < 64) {
        double v = csum[tid];
#pragma unroll
        for (int off = 1; off < 64; off <<= 1) {
            double t = __shfl_down(v, off, 64);
            if (tid + off < 64) v += t;
        }
        Rbef[tid] = v;
    }
    __syncthreads();

    float Af2[4], Sb2[4];
    double Rb = Rbef[c];
#pragma unroll
    for (int j = 0; j < 4; ++j) {
        float Af = -__expf(Alog[d * NSTATE + 4 * l + j]);
        double A2 = (double)Af * LOG2E;
        Af2[j] = (float)A2;
        Sb2[j] = (float)(A2 * Rb);
    }
    float Dv = Dp[d];

    float P = 0.f;
    f32x4 Tn = {0.f, 0.f, 0.f, 0.f};
#pragma unroll 1
    for (int t4 = 0; t4 < 4; ++t4) {
        f32x4 rdv = dp[t4];
        ushort4 uv = *(const ushort4*)(up + t4 * 4);
        float ru[4] = {bf2f(uv.x), bf2f(uv.y), bf2f(uv.z), bf2f(uv.w)};
        f32x4 Bq[4];
#pragma unroll
        for (int k = 0; k < 4; ++k) Bq[k] = Bp[(t4 * 4 + k) * 4];
#pragma unroll
        for (int k = 0; k < 4; ++k) {
            float dlt = rdv[k];
            P += dlt;
            float du = dlt * ru[k];
#pragma unroll
            for (int j = 0; j < 4; ++j) {
                float e = EXP2F(fmaf(-Af2[j], P, Sb2[j]));
                Tn[j] = fmaf(du * Bq[k][j], e, Tn[j]);
            }
        }
    }
    *(f32x4*)&TcL[c * 20 + 4 * l] = Tn;
    __syncthreads();

    {
        f32x4 v = *(const f32x4*)&TcL[lane * 20 + 4 * w];
#pragma unroll
        for (int off = 1; off < 64; off <<= 1) {
            f32x4 t = shflup4(v, off);
            if (lane >= off) v += t;
        }
        f32x4 ex = shflup4(v, 1);
        if (lane == 0) ex = (f32x4){0.f, 0.f, 0.f, 0.f};
        *(f32x4*)&TcL[lane * 20 + 4 * w] = ex;
    }
    __syncthreads();
    f32x4 num = *(const f32x4*)&TcL[c * 20 + 4 * l];

    P = 0.f;
#pragma unroll 1
    for (int t4 = 0; t4 < 4; ++t4) {
        f32x4 rdv = dp[t4];
        ushort4 uv = *(const ushort4*)(up + t4 * 4);
        float ru[4] = {bf2f(uv.x), bf2f(uv.y), bf2f(uv.z), bf2f(uv.w)};
        f32x4 Bq[4], Cq[4];
#pragma unroll
        for (int k = 0; k < 4; ++k) {
            Bq[k] = Bp[(t4 * 4 + k) * 4];
            Cq[k] = Cp[(t4 * 4 + k) * 4];
        }
#pragma unroll
        for (int k = 0; k < 4; ++k) {
            float dlt = rdv[k];
            P += dlt;
            float du = dlt * ru[k];
            float psum = 0.f;
#pragma unroll
            for (int j = 0; j < 4; ++j) {
                float e = EXP2F(fmaf(-Af2[j], P, Sb2[j]));
                num[j] = fmaf(du * Bq[k][j], e, num[j]);
                float rr = __builtin_amdgcn_rcpf(e + 1e-12f);
                psum = fmaf(num[j] * rr, Cq[k][j], psum);
            }
            psum += __shfl_xor(psum, 1);
            psum += __shfl_xor(psum, 2);
            if (l == 0) syp[c * 17 + t4 * 4 + k] = fmaf(ru[k], Dv, psum);
        }
    }
    __syncthreads();
    {
        int cc = tid >> 2, oo = (tid & 3) * 4;
        const float* sp = &syp[cc * 17 + oo];
        ushort4 o;
        o.x = f2bf(sp[0]);
        o.y = f2bf(sp[1]);
        o.z = f2bf(sp[2]);
        o.w = f2bf(sp[3]);
        *reinterpret_cast<ushort4*>(&yTbf[(size_t)d * MTOT + m0 + tid * 4]) = o;
    }
}

// ---------------- Kernel 4: gemm, A staged directly from yTbf via u32 pair-packing ----------------
__global__ __launch_bounds__(256) void k_gemm(const unsigned short* __restrict__ yT,
                                              const unsigned short* __restrict__ B,
                                              const float* __restrict__ bias,
                                              float* __restrict__ out) {
    __shared__ unsigned int P[32 * 68];
    __shared__ unsigned short Bs[64 * 64];
    const int GN = 1024, GK = 1024;
    int bm = blockIdx.y * 64;
    int bn = blockIdx.x * 64;
    int tid = threadIdx.x;
    int lane = tid & 63;
    int w = tid >> 6;
    int wm = w >> 1, wn = w & 1;
    int r = lane & 15, kb = lane >> 4;

    f32x4 acc[2][2];
#pragma unroll
    for (int mf = 0; mf < 2; ++mf)
#pragma unroll
        for (int nf = 0; nf < 2; ++nf) acc[mf][nf] = (f32x4){0.f, 0.f, 0.f, 0.f};

    ushort4 rya[2], ryb[2];
    s16x8 rbv[2];
    auto stage_load = [&](int k0) {
#pragma unroll
        for (int i = 0; i < 2; ++i) {
            int slot = tid + i * 256;
            int p = slot >> 4, mq = (slot & 15) * 4;
            rya[i] = *(const ushort4*)&yT[(size_t)(k0 + 2 * p) * MTOT + bm + mq];
            ryb[i] = *(const ushort4*)&yT[(size_t)(k0 + 2 * p + 1) * MTOT + bm + mq];
            rbv[i] = *(const s16x8*)&B[(size_t)(bn + (slot >> 3)) * GK + k0 + (slot & 7) * 8];
        }
    };

    stage_load(0);
    for (int k0 = 0; k0 < GK; k0 += 64) {
        __syncthreads();
#pragma unroll
        for (int i = 0; i < 2; ++i) {
            int slot = tid + i * 256;
            int p = slot >> 4, mq = (slot & 15) * 4;
            u32x4 pk;
            pk[0] = (unsigned int)rya[i].x | ((unsigned int)ryb[i].x << 16);
            pk[1] = (unsigned int)rya[i].y | ((unsigned int)ryb[i].y << 16);
            pk[2] = (unsigned int)rya[i].z | ((unsigned int)ryb[i].z << 16);
            pk[3] = (unsigned int)rya[i].w | ((unsigned int)ryb[i].w << 16);
            *(u32x4*)&P[p * 68 + mq] = pk;
            int row = slot >> 3;
            int dstB = row * 128 + (((slot & 7) * 16) ^ ((row & 7) << 4));
            *(s16x8*)((char*)Bs + dstB) = rbv[i];
        }
        __syncthreads();
        if (k0 + 64 < GK) stage_load(k0 + 64);
#pragma unroll
        for (int ks = 0; ks < 2; ++ks) {
            int sw = (ks * 64 + kb * 16) ^ ((r & 7) << 4);
            s16x8 af[2], bfr[2];
#pragma unroll
            for (int mf = 0; mf < 2; ++mf) {
                int base = (ks * 16 + kb * 4) * 68 + wm * 32 + mf * 16 + r;
                u32x4 av;
                av[0] = P[base];
                av[1] = P[base + 68];
                av[2] = P[base + 136];
                av[3] = P[base + 204];
                af[mf] = __builtin_bit_cast(s16x8, av);
            }
#pragma unroll
            for (int nf = 0; nf < 2; ++nf)
                bfr[nf] = *(const s16x8*)((char*)Bs + (wn * 32 + nf * 16 + r) * 128 + sw);
#pragma unroll
            for (int mf = 0; mf < 2; ++mf)
#pragma unroll
                for (int nf = 0; nf < 2; ++nf)
                    acc[mf][nf] = __builtin_amdgcn_mfma_f32_16x16x32_bf16(af[mf], bfr[nf], acc[mf][nf], 0, 0, 0);
        }
    }
#pragma unroll
    for (int nf = 0; nf < 2; ++nf) {
        float bb = bias[bn + wn * 32 + nf * 16 + r];
#pragma unroll
        for (int mf = 0; mf < 2; ++mf)
#pragma unroll
            for (int j = 0; j < 4; ++j)
                out[(size_t)(bm + wm * 32 + mf * 16 + kb * 4 + j) * GN + bn + wn * 32 + nf * 16 + r] =
                    acc[mf][nf][j] + bb;
    }
}

extern "C" void kernel_launch(void* const* d_in, const int* in_sizes, int n_in,
                              void* d_out, int out_size, void* d_ws, size_t ws_size,
                              hipStream_t stream) {
    const float* x    = (const float*)d_in[0];
    const float* Wx   = (const float*)d_in[1];
    const float* Wdt  = (const float*)d_in[2];
    const float* bdt  = (const float*)d_in[3];
    const float* Alog = (const float*)d_in[4];
    const float* Dp   = (const float*)d_in[5];
    const float* Wout = (const float*)d_in[6];
    const float* bout = (const float*)d_in[7];
    float* out = (float*)d_out;

    float* deltaT = (float*)d_ws;                          // 1024*2048 f
    float* bpk    = deltaT + 1024 * 2048;                  // 2048*16 f
    float* cpk    = bpk + 2048 * 16;                       // 2048*16 f
    float* part   = cpk + 2048 * 16;                       // 4*2048*96 f
    unsigned short* xTbf  = (unsigned short*)(part + 4 * 2048 * 96);  // 1024*2048
    unsigned short* WdtTh = xTbf + 1024 * 2048;            // 1024*64
    unsigned short* WdtTl = WdtTh + 1024 * 64;
    unsigned short* yTbf  = WdtTl + 1024 * 64;             // 1024*2048
    unsigned short* WbfT  = yTbf + 1024 * 2048;            // 1024*1024

    k_xdbl<<<576, 256, 0, stream>>>(x, Wx, Wdt, Wout, part, WdtTh, WdtTl, WbfT);
    k_delta2<<<768, 256, 0, stream>>>(part, WdtTh, WdtTl, bdt, x, deltaT, bpk, cpk, xTbf);
    k_scan3<<<2048, 256, 0, stream>>>(deltaT, xTbf, bpk, cpk, Alog, Dp, yTbf);
    k_gemm<<<dim3(16, 32), 256, 0, stream>>>(yTbf, WbfT, bout, out);
}

// Round 14
// 64.562 us; speedup vs baseline: 1.2489x; 1.0141x over previous
//
#include <hip/hip_runtime.h>
#include <hip/hip_bf16.h>

// b=2, L=1024, d=1024, dt_rank=64, n=16, E=96
#define LSEQ 1024
#define DMODEL 1024
#define NSTATE 16
#define DTRANK 64
#define ECOL 96
#define MTOT 2048

typedef short s16x8 __attribute__((ext_vector_type(8)));
typedef float f32x4 __attribute__((ext_vector_type(4)));
typedef unsigned int u32x4 __attribute__((ext_vector_type(4)));

#if __has_builtin(__builtin_amdgcn_exp2f)
#define EXP2F(x) __builtin_amdgcn_exp2f(x)
#else
#define EXP2F(x) exp2f(x)
#endif
#define LOG2E 1.4426950408889634

__device__ inline unsigned short f2bf(float f) {
    unsigned int u = __builtin_bit_cast(unsigned int, f);
    u += 0x7FFFu + ((u >> 16) & 1u);
    return (unsigned short)(u >> 16);
}
__device__ inline float bf2f(unsigned short h) {
    unsigned int u = ((unsigned int)h) << 16;
    return __builtin_bit_cast(float, u);
}
__device__ inline f32x4 bfq2f(ushort4 h) {
    f32x4 r;
    r[0] = bf2f(h.x); r[1] = bf2f(h.y); r[2] = bf2f(h.z); r[3] = bf2f(h.w);
    return r;
}

__device__ inline f32x4 shflup4(f32x4 v, int off) {
    f32x4 r;
    r[0] = __shfl_up(v[0], off, 64);
    r[1] = __shfl_up(v[1], off, 64);
    r[2] = __shfl_up(v[2], off, 64);
    r[3] = __shfl_up(v[3], off, 64);
    return r;
}

// ============ Kernel 1: xdbl split-K MFMA (256 vb) + WdtT riders (64) + WbfT riders (256) ============
__global__ __launch_bounds__(256) void k_xdbl(const float* __restrict__ x,
                                              const float* __restrict__ Wx,
                                              const float* __restrict__ Wdt,
                                              const float* __restrict__ Wout,
                                              float* __restrict__ part,
                                              unsigned short* __restrict__ WdtTh,
                                              unsigned short* __restrict__ WdtTl,
                                              unsigned short* __restrict__ WbfT) {
    __shared__ alignas(16) char pool[32768];
    int bid = blockIdx.x;
    int tid = threadIdx.x;

    if (bid >= 256) {
        float (*t)[65] = (float (*)[65])pool;
        if (bid < 320) {  // WdtT: Wdt [64][1024] -> [d][r] bf16 h/l
            int id3 = bid - 256;
            int d0 = (id3 & 31) * 32, r0 = (id3 >> 5) * 32;
            int tx = tid & 31, ty = tid >> 5;
#pragma unroll
            for (int j = 0; j < 32; j += 8)
                t[ty + j][tx] = Wdt[(size_t)(r0 + ty + j) * 1024 + d0 + tx];
            __syncthreads();
#pragma unroll
            for (int j = 0; j < 32; j += 8) {
                float v = t[tx][ty + j];
                unsigned short h = f2bf(v);
                WdtTh[(size_t)(d0 + ty + j) * 64 + r0 + tx] = h;
                WdtTl[(size_t)(d0 + ty + j) * 64 + r0 + tx] = f2bf(v - bf2f(h));
            }
        } else {          // WbfT: Wout [k][e] -> [e][k] bf16
            int id4 = bid - 320;
            int e0 = (id4 & 15) * 64, k0 = (id4 >> 4) * 64;
            int tx = tid & 63, ty = tid >> 6;
#pragma unroll
            for (int j = 0; j < 64; j += 4)
                t[ty + j][tx] = Wout[(size_t)(k0 + ty + j) * 1024 + e0 + tx];
            __syncthreads();
#pragma unroll
            for (int j = 0; j < 64; j += 4)
                WbfT[(size_t)(e0 + ty + j) * 1024 + k0 + tx] = f2bf(t[tx][ty + j]);
        }
        return;
    }

    unsigned short* Ah = (unsigned short*)pool;
    unsigned short* Al = (unsigned short*)(pool + 4096);
    unsigned short* Bh = (unsigned short*)(pool + 8192);
    unsigned short* Bl = (unsigned short*)(pool + 20480);
    int bm = (bid >> 2) * 32;
    int slice = bid & 3;
    int lane = tid & 63, w = tid >> 6;
    int wm = w >> 1, wn = w & 1;
    int r = lane & 15, kb = lane >> 4;

    f32x4 acc[3];
#pragma unroll
    for (int nf = 0; nf < 3; ++nf) acc[nf] = (f32x4){0.f, 0.f, 0.f, 0.f};

#pragma unroll 1
    for (int kc = 0; kc < 4; ++kc) {
        int kbase = slice * 256 + kc * 64;
        __syncthreads();
        {   // stage A: x fp32 -> h/l regs -> swizzled LDS
            int row = tid >> 3, cc = tid & 7;
            size_t src = (size_t)(bm + row) * 1024 + kbase + cc * 8;
            float4 v0 = *(const float4*)&x[src];
            float4 v1 = *(const float4*)&x[src + 4];
            float vv[8] = {v0.x, v0.y, v0.z, v0.w, v1.x, v1.y, v1.z, v1.w};
            s16x8 h, lo;
#pragma unroll
            for (int j = 0; j < 8; ++j) {
                unsigned short hb = f2bf(vv[j]);
                h[j] = (short)hb;
                lo[j] = (short)f2bf(vv[j] - bf2f(hb));
            }
            int dstB = row * 128 + ((cc * 16) ^ ((row & 7) << 4));
            *(s16x8*)((char*)Ah + dstB) = h;
            *(s16x8*)((char*)Al + dstB) = lo;
        }
        // stage B: Wx [k][96] fp32 -> transpose+split -> swizzled LDS [e][k] h/l
#pragma unroll
        for (int it = 0; it < 3; ++it) {
            int item = it * 256 + tid;
            int e = item % 96;
            int cc = item / 96;
            s16x8 h, lo;
#pragma unroll
            for (int j = 0; j < 8; ++j) {
                float v = Wx[(size_t)(kbase + cc * 8 + j) * 96 + e];
                unsigned short hb = f2bf(v);
                h[j] = (short)hb;
                lo[j] = (short)f2bf(v - bf2f(hb));
            }
            int dstB = e * 128 + ((cc * 16) ^ ((e & 7) << 4));
            *(s16x8*)((char*)Bh + dstB) = h;
            *(s16x8*)((char*)Bl + dstB) = lo;
        }
        __syncthreads();
#pragma unroll
        for (int ks = 0; ks < 2; ++ks) {
            int sw = (ks * 64 + kb * 16) ^ ((r & 7) << 4);
            s16x8 a_h = *(const s16x8*)((char*)Ah + (wm * 16 + r) * 128 + sw);
            s16x8 a_l = *(const s16x8*)((char*)Al + (wm * 16 + r) * 128 + sw);
#pragma unroll
            for (int nf = 0; nf < 3; ++nf) {
                int brow = wn * 48 + nf * 16 + r;
                s16x8 b_h = *(const s16x8*)((char*)Bh + brow * 128 + sw);
                s16x8 b_l = *(const s16x8*)((char*)Bl + brow * 128 + sw);
                acc[nf] = __builtin_amdgcn_mfma_f32_16x16x32_bf16(a_h, b_h, acc[nf], 0, 0, 0);
                acc[nf] = __builtin_amdgcn_mfma_f32_16x16x32_bf16(a_h, b_l, acc[nf], 0, 0, 0);
                acc[nf] = __builtin_amdgcn_mfma_f32_16x16x32_bf16(a_l, b_h, acc[nf], 0, 0, 0);
            }
        }
    }
    float* pb = part + (size_t)slice * 2048 * 96;
#pragma unroll
    for (int nf = 0; nf < 3; ++nf)
#pragma unroll
        for (int j = 0; j < 4; ++j)
            pb[(size_t)(bm + wm * 16 + kb * 4 + j) * 96 + wn * 48 + nf * 16 + r] = acc[nf][j];
}

// ============ Kernel 2: delta2 (256 vb) + x->xTbf transpose riders (512); bpk/cpk now bf16 ============
__global__ __launch_bounds__(256) void k_delta2(const float* __restrict__ part,
                                                const unsigned short* __restrict__ WdtTh,
                                                const unsigned short* __restrict__ WdtTl,
                                                const float* __restrict__ bdt,
                                                const float* __restrict__ x,
                                                float* __restrict__ deltaT,
                                                unsigned short* __restrict__ bpk,
                                                unsigned short* __restrict__ cpk,
                                                unsigned short* __restrict__ xTbf) {
    __shared__ alignas(16) char pool[34816];
    int bid = blockIdx.x;
    int tid = threadIdx.x;

    if (bid >= 256) {  // rider: x [m][d] fp32 -> xTbf [d][m] bf16
        float (*t)[65] = (float (*)[65])pool;
        int id = bid - 256;
        int d0 = (id & 15) * 64, m0 = (id >> 4) * 64;
        int tx = tid & 63, ty = tid >> 6;
#pragma unroll
        for (int j = 0; j < 64; j += 4)
            t[ty + j][tx] = x[(size_t)(m0 + ty + j) * 1024 + d0 + tx];
        __syncthreads();
#pragma unroll
        for (int j = 0; j < 64; j += 4)
            xTbf[(size_t)(d0 + ty + j) * 2048 + m0 + tx] = f2bf(t[tx][ty + j]);
        return;
    }

    unsigned short* Ah = (unsigned short*)pool;
    unsigned short* Al = (unsigned short*)(pool + 16384);
    float (*slab)[32][68] = (float (*)[32][68])pool;
    int bxq = bid & 15, byq = bid >> 4;
    int bm = byq * 128;
    int bn = bxq * 64;
    int lane = tid & 63, w = tid >> 6;
    int wm = w >> 1, wn = w & 1;
    int r = lane & 15, kb = lane >> 4;

#pragma unroll
    for (int i = 0; i < 8; ++i) {
        int q = tid + i * 256;
        int row = q >> 4, c4 = q & 15;
        size_t off = (size_t)(bm + row) * 96 + c4 * 4;
        f32x4 v = *(const f32x4*)&part[off];
#pragma unroll
        for (int s = 1; s < 4; ++s) v += *(const f32x4*)&part[(size_t)s * 2048 * 96 + off];
        ushort4 h4, l4;
        h4.x = f2bf(v[0]); l4.x = f2bf(v[0] - bf2f(h4.x));
        h4.y = f2bf(v[1]); l4.y = f2bf(v[1] - bf2f(h4.y));
        h4.z = f2bf(v[2]); l4.z = f2bf(v[2] - bf2f(h4.z));
        h4.w = f2bf(v[3]); l4.w = f2bf(v[3] - bf2f(h4.w));
        int dstB = row * 128 + ((c4 * 8) ^ ((row & 7) << 4));
        *(ushort4*)((char*)Ah + dstB) = h4;
        *(ushort4*)((char*)Al + dstB) = l4;
    }
    if (bxq == 0) {
#pragma unroll
        for (int i = 0; i < 4; ++i) {
            int q = tid + i * 256;
            int row = q >> 3, c4 = q & 7;
            size_t off = (size_t)(bm + row) * 96 + 64 + c4 * 4;
            f32x4 v = *(const f32x4*)&part[off];
#pragma unroll
            for (int s = 1; s < 4; ++s) v += *(const f32x4*)&part[(size_t)s * 2048 * 96 + off];
            ushort4 o;
            o.x = f2bf(v[0]); o.y = f2bf(v[1]); o.z = f2bf(v[2]); o.w = f2bf(v[3]);
            if (c4 < 4) *(ushort4*)&bpk[(size_t)(bm + row) * 16 + c4 * 4] = o;
            else        *(ushort4*)&cpk[(size_t)(bm + row) * 16 + (c4 - 4) * 4] = o;
        }
    }
    __syncthreads();

    f32x4 acc[4][2];
#pragma unroll
    for (int mf = 0; mf < 4; ++mf)
#pragma unroll
        for (int nf = 0; nf < 2; ++nf) acc[mf][nf] = (f32x4){0.f, 0.f, 0.f, 0.f};

#pragma unroll
    for (int ks = 0; ks < 2; ++ks) {
        int sw = (ks * 64 + kb * 16) ^ ((r & 7) << 4);
        s16x8 Afh[4], Afl[4], Bh[2], Bl[2];
#pragma unroll
        for (int mf = 0; mf < 4; ++mf) {
            int arow = wm * 64 + mf * 16 + r;
            Afh[mf] = *(const s16x8*)((char*)Ah + arow * 128 + sw);
            Afl[mf] = *(const s16x8*)((char*)Al + arow * 128 + sw);
        }
#pragma unroll
        for (int nf = 0; nf < 2; ++nf) {
            size_t b = (size_t)(bn + wn * 32 + nf * 16 + r) * 64 + ks * 32 + kb * 8;
            Bh[nf] = *(const s16x8*)&WdtTh[b];
            Bl[nf] = *(const s16x8*)&WdtTl[b];
        }
#pragma unroll
        for (int mf = 0; mf < 4; ++mf)
#pragma unroll
            for (int nf = 0; nf < 2; ++nf) {
                acc[mf][nf] = __builtin_amdgcn_mfma_f32_16x16x32_bf16(Afh[mf], Bh[nf], acc[mf][nf], 0, 0, 0);
                acc[mf][nf] = __builtin_amdgcn_mfma_f32_16x16x32_bf16(Afh[mf], Bl[nf], acc[mf][nf], 0, 0, 0);
                acc[mf][nf] = __builtin_amdgcn_mfma_f32_16x16x32_bf16(Afl[mf], Bh[nf], acc[mf][nf], 0, 0, 0);
            }
    }
    __syncthreads();

#pragma unroll
    for (int nf = 0; nf < 2; ++nf) {
        float bb = bdt[bn + wn * 32 + nf * 16 + r];
#pragma unroll
        for (int mf = 0; mf < 4; ++mf)
#pragma unroll
            for (int j = 0; j < 4; ++j) {
                float z = acc[mf][nf][j] + bb;
                float sp = fmaxf(z, 0.f) + log1pf(expf(-fabsf(z)));
                slab[w][nf * 16 + r][mf * 16 + kb * 4 + j] = sp;
            }
    }
#pragma unroll
    for (int i = 0; i < 8; ++i) {
        int idx = i * 64 + lane;
        int dl = idx >> 4, mq = (idx & 15) * 4;
        f32x4 v = *(const f32x4*)&slab[w][dl][mq];
        *(f32x4*)&deltaT[(size_t)(bn + wn * 32 + dl) * MTOT + bm + wm * 64 + mq] = v;
    }
}

// ---------------- Kernel 3: chunked selective scan (bf16 u, bf16 B/C, base-2 exp) ----------------
__global__ __launch_bounds__(256) void k_scan3(const float* __restrict__ deltaT,
                                               const unsigned short* __restrict__ xTbf,
                                               const unsigned short* __restrict__ bpk,
                                               const unsigned short* __restrict__ cpk,
                                               const float* __restrict__ Alog,
                                               const float* __restrict__ Dp,
                                               unsigned short* __restrict__ yTbf) {
    __shared__ double csum[64];
    __shared__ double Rbef[64];
    __shared__ float TcL[64 * 20];
    __shared__ float syp[64 * 17];

    int tid = threadIdx.x;
    int c = tid >> 2, l = tid & 3;
    int w = tid >> 6, lane = tid & 63;
    int d = blockIdx.x & 1023, b = blockIdx.x >> 10;
    int m0 = b * 1024;

    const f32x4* dp = (const f32x4*)(deltaT + (size_t)d * MTOT + m0 + c * 16);
    const unsigned short* up = xTbf + (size_t)d * MTOT + m0 + c * 16;
    const unsigned short* Bp = bpk + (size_t)(m0 + c * 16) * 16 + l * 4;
    const unsigned short* Cp = cpk + (size_t)(m0 + c * 16) * 16 + l * 4;

    double dsum = 0.0;
#pragma unroll
    for (int i = 0; i < 4; ++i) {
        f32x4 v = dp[i];
        dsum += (double)v[0] + (double)v[1] + (double)v[2] + (double)v[3];
    }
    if (l == 0) csum[c] = dsum;
    __syncthreads();
    if (tid < 64) {
        double v = csum[tid];
#pragma unroll
        for (int off = 1; off < 64; off <<= 1) {
            double t = __shfl_down(v, off, 64);
            if (tid + off < 64) v += t;
        }
        Rbef[tid] = v;
    }
    __syncthreads();

    float Af2[4], Sb2[4];
    double Rb = Rbef[c];
#pragma unroll
    for (int j = 0; j < 4; ++j) {
        float Af = -__expf(Alog[d * NSTATE + 4 * l + j]);
        double A2 = (double)Af * LOG2E;
        Af2[j] = (float)A2;
        Sb2[j] = (float)(A2 * Rb);
    }
    float Dv = Dp[d];

    float P = 0.f;
    f32x4 Tn = {0.f, 0.f, 0.f, 0.f};
#pragma unroll 1
    for (int t4 = 0; t4 < 4; ++t4) {
        f32x4 rdv = dp[t4];
        ushort4 uv = *(const ushort4*)(up + t4 * 4);
        float ru[4] = {bf2f(uv.x), bf2f(uv.y), bf2f(uv.z), bf2f(uv.w)};
        f32x4 Bq[4];
#pragma unroll
        for (int k = 0; k < 4; ++k)
            Bq[k] = bfq2f(*(const ushort4*)(Bp + (size_t)(t4 * 4 + k) * 16));
#pragma unroll
        for (int k = 0; k < 4; ++k) {
            float dlt = rdv[k];
            P += dlt;
            float du = dlt * ru[k];
#pragma unroll
            for (int j = 0; j < 4; ++j) {
                float e = EXP2F(fmaf(-Af2[j], P, Sb2[j]));
                Tn[j] = fmaf(du * Bq[k][j], e, Tn[j]);
            }
        }
    }
    *(f32x4*)&TcL[c * 20 + 4 * l] = Tn;
    __syncthreads();

    {
        f32x4 v = *(const f32x4*)&TcL[lane * 20 + 4 * w];
#pragma unroll
        for (int off = 1; off < 64; off <<= 1) {
            f32x4 t = shflup4(v, off);
            if (lane >= off) v += t;
        }
        f32x4 ex = shflup4(v, 1);
        if (lane == 0) ex = (f32x4){0.f, 0.f, 0.f, 0.f};
        *(f32x4*)&TcL[lane * 20 + 4 * w] = ex;
    }
    __syncthreads();
    f32x4 num = *(const f32x4*)&TcL[c * 20 + 4 * l];

    P = 0.f;
#pragma unroll 1
    for (int t4 = 0; t4 < 4; ++t4) {
        f32x4 rdv = dp[t4];
        ushort4 uv = *(const ushort4*)(up + t4 * 4);
        float ru[4] = {bf2f(uv.x), bf2f(uv.y), bf2f(uv.z), bf2f(uv.w)};
        f32x4 Bq[4], Cq[4];
#pragma unroll
        for (int k = 0; k < 4; ++k) {
            Bq[k] = bfq2f(*(const ushort4*)(Bp + (size_t)(t4 * 4 + k) * 16));
            Cq[k] = bfq2f(*(const ushort4*)(Cp + (size_t)(t4 * 4 + k) * 16));
        }
#pragma unroll
        for (int k = 0; k < 4; ++k) {
            float dlt = rdv[k];
            P += dlt;
            float du = dlt * ru[k];
            float psum = 0.f;
#pragma unroll
            for (int j = 0; j < 4; ++j) {
                float e = EXP2F(fmaf(-Af2[j], P, Sb2[j]));
                num[j] = fmaf(du * Bq[k][j], e, num[j]);
                float rr = __builtin_amdgcn_rcpf(e + 1e-12f);
                psum = fmaf(num[j] * rr, Cq[k][j], psum);
            }
            psum += __shfl_xor(psum, 1);
            psum += __shfl_xor(psum, 2);
            if (l == 0) syp[c * 17 + t4 * 4 + k] = fmaf(ru[k], Dv, psum);
        }
    }
    __syncthreads();
    {
        int cc = tid >> 2, oo = (tid & 3) * 4;
        const float* sp = &syp[cc * 17 + oo];
        ushort4 o;
        o.x = f2bf(sp[0]);
        o.y = f2bf(sp[1]);
        o.z = f2bf(sp[2]);
        o.w = f2bf(sp[3]);
        *reinterpret_cast<ushort4*>(&yTbf[(size_t)d * MTOT + m0 + tid * 4]) = o;
    }
}

// ---------------- Kernel 4: gemm, double-buffered LDS (1 barrier/K-step) ----------------
__global__ __launch_bounds__(256) void k_gemm(const unsigned short* __restrict__ yT,
                                              const unsigned short* __restrict__ B,
                                              const float* __restrict__ bias,
                                              float* __restrict__ out) {
    __shared__ unsigned int P[2][32 * 68];
    __shared__ unsigned short Bs[2][64 * 64];
    const int GN = 1024, GK = 1024;
    int bm = blockIdx.y * 64;
    int bn = blockIdx.x * 64;
    int tid = threadIdx.x;
    int lane = tid & 63;
    int w = tid >> 6;
    int wm = w >> 1, wn = w & 1;
    int r = lane & 15, kb = lane >> 4;

    f32x4 acc[2][2];
#pragma unroll
    for (int mf = 0; mf < 2; ++mf)
#pragma unroll
        for (int nf = 0; nf < 2; ++nf) acc[mf][nf] = (f32x4){0.f, 0.f, 0.f, 0.f};

    ushort4 rya[2], ryb[2];
    s16x8 rbv[2];
    auto stage_load = [&](int k0) {
#pragma unroll
        for (int i = 0; i < 2; ++i) {
            int slot = tid + i * 256;
            int p = slot >> 4, mq = (slot & 15) * 4;
            rya[i] = *(const ushort4*)&yT[(size_t)(k0 + 2 * p) * MTOT + bm + mq];
            ryb[i] = *(const ushort4*)&yT[(size_t)(k0 + 2 * p + 1) * MTOT + bm + mq];
            rbv[i] = *(const s16x8*)&B[(size_t)(bn + (slot >> 3)) * GK + k0 + (slot & 7) * 8];
        }
    };

    stage_load(0);
    int cur = 0;
    for (int k0 = 0; k0 < GK; k0 += 64) {
#pragma unroll
        for (int i = 0; i < 2; ++i) {
            int slot = tid + i * 256;
            int p = slot >> 4, mq = (slot & 15) * 4;
            u32x4 pk;
            pk[0] = (unsigned int)rya[i].x | ((unsigned int)ryb[i].x << 16);
            pk[1] = (unsigned int)rya[i].y | ((unsigned int)ryb[i].y << 16);
            pk[2] = (unsigned int)rya[i].z | ((unsigned int)ryb[i].z << 16);
            pk[3] = (unsigned int)rya[i].w | ((unsigned int)ryb[i].w << 16);
            *(u32x4*)&P[cur][p * 68 + mq] = pk;
            int row = slot >> 3;
            int dstB = row * 128 + (((slot & 7) * 16) ^ ((row & 7) << 4));
            *(s16x8*)((char*)&Bs[cur][0] + dstB) = rbv[i];
        }
        __syncthreads();
        if (k0 + 64 < GK) stage_load(k0 + 64);
#pragma unroll
        for (int ks = 0; ks < 2; ++ks) {
            int sw = (ks * 64 + kb * 16) ^ ((r & 7) << 4);
            s16x8 af[2], bfr[2];
#pragma unroll
            for (int mf = 0; mf < 2; ++mf) {
                int base = (ks * 16 + kb * 4) * 68 + wm * 32 + mf * 16 + r;
                u32x4 av;
                av[0] = P[cur][base];
                av[1] = P[cur][base + 68];
                av[2] = P[cur][base + 136];
                av[3] = P[cur][base + 204];
                af[mf] = __builtin_bit_cast(s16x8, av);
            }
#pragma unroll
            for (int nf = 0; nf < 2; ++nf)
                bfr[nf] = *(const s16x8*)((char*)&Bs[cur][0] + (wn * 32 + nf * 16 + r) * 128 + sw);
#pragma unroll
            for (int mf = 0; mf < 2; ++mf)
#pragma unroll
                for (int nf = 0; nf < 2; ++nf)
                    acc[mf][nf] = __builtin_amdgcn_mfma_f32_16x16x32_bf16(af[mf], bfr[nf], acc[mf][nf], 0, 0, 0);
        }
        cur ^= 1;
    }
#pragma unroll
    for (int nf = 0; nf < 2; ++nf) {
        float bb = bias[bn + wn * 32 + nf * 16 + r];
#pragma unroll
        for (int mf = 0; mf < 2; ++mf)
#pragma unroll
            for (int j = 0; j < 4; ++j)
                out[(size_t)(bm + wm * 32 + mf * 16 + kb * 4 + j) * GN + bn + wn * 32 + nf * 16 + r] =
                    acc[mf][nf][j] + bb;
    }
}

extern "C" void kernel_launch(void* const* d_in, const int* in_sizes, int n_in,
                              void* d_out, int out_size, void* d_ws, size_t ws_size,
                              hipStream_t stream) {
    const float* x    = (const float*)d_in[0];
    const float* Wx   = (const float*)d_in[1];
    const float* Wdt  = (const float*)d_in[2];
    const float* bdt  = (const float*)d_in[3];
    const float* Alog = (const float*)d_in[4];
    const float* Dp   = (const float*)d_in[5];
    const float* Wout = (const float*)d_in[6];
    const float* bout = (const float*)d_in[7];
    float* out = (float*)d_out;

    float* deltaT = (float*)d_ws;                          // 1024*2048 f
    float* part   = deltaT + 1024 * 2048;                  // 4*2048*96 f
    unsigned short* bpk   = (unsigned short*)(part + 4 * 2048 * 96);  // 2048*16 bf16
    unsigned short* cpk   = bpk + 2048 * 16;
    unsigned short* xTbf  = cpk + 2048 * 16;               // 1024*2048
    unsigned short* WdtTh = xTbf + 1024 * 2048;            // 1024*64
    unsigned short* WdtTl = WdtTh + 1024 * 64;
    unsigned short* yTbf  = WdtTl + 1024 * 64;             // 1024*2048
    unsigned short* WbfT  = yTbf + 1024 * 2048;            // 1024*1024

    k_xdbl<<<576, 256, 0, stream>>>(x, Wx, Wdt, Wout, part, WdtTh, WdtTl, WbfT);
    k_delta2<<<768, 256, 0, stream>>>(part, WdtTh, WdtTl, bdt, x, deltaT, bpk, cpk, xTbf);
    k_scan3<<<2048, 256, 0, stream>>>(deltaT, xTbf, bpk, cpk, Alog, Dp, yTbf);
    k_gemm<<<dim3(16, 32), 256, 0, stream>>>(yTbf, WbfT, bout, out);
}